// Round 3
// baseline (5980.781 us; speedup 1.0000x reference)
//
#include <hip/hip_runtime.h>
#include <hip/hip_bf16.h>

#define D_MODEL 1024
#define N_HEADS 16
#define DK      64
#define SEQ     2048
#define BATCH   2
#define D_FF    4096
#define ROWS    (BATCH*SEQ)   // 4096
#define LN_EPS  1e-6f

typedef __hip_bfloat16 bf16;

__device__ inline float bf2f(unsigned short u){ return __uint_as_float(((unsigned)u) << 16); }
__device__ inline float toF(bf16 v){ return __bfloat162float(v); }

struct F4 { float x, y, z, w; };

// Load 4 consecutive elements starting at element index idx (idx % 4 == 0),
// interpreting the buffer as fp32 (f32=true) or bf16 (f32=false).
__device__ inline F4 ld4(const void* p, size_t idx, bool f32) {
    F4 r;
    if (f32) {
        const float4 v = *reinterpret_cast<const float4*>((const float*)p + idx);
        r.x = v.x; r.y = v.y; r.z = v.z; r.w = v.w;
    } else {
        const ushort4 v = *reinterpret_cast<const ushort4*>((const bf16*)p + idx);
        r.x = bf2f(v.x); r.y = bf2f(v.y); r.z = bf2f(v.z); r.w = bf2f(v.w);
    }
    return r;
}
__device__ inline float ld1(const void* p, size_t idx, bool f32) {
    return f32 ? ((const float*)p)[idx] : toF(((const bf16*)p)[idx]);
}

// Dtype probe: scan first 8192 elems of x as bf16. Real bf16 normals are |v|<6;
// fp32 bits misread as bf16 give Inf/NaN/huge with overwhelming probability.
__global__ void probe_kernel(const void* __restrict__ xp, int* __restrict__ flag) {
    __shared__ int hit;
    if (threadIdx.x == 0) hit = 0;
    __syncthreads();
    const bf16* p = (const bf16*)xp;
    int bad = 0;
    for (int i = threadIdx.x; i < 8192; i += 256) {
        float v = fabsf(toF(p[i]));
        if (!(v <= 1e5f)) bad = 1;   // catches huge AND NaN
    }
    if (bad) atomicOr(&hit, 1);
    __syncthreads();
    if (threadIdx.x == 0) *flag = hit;   // 1 => inputs are fp32
}

// C[M,N] (always bf16, in ws) = A[M,K] @ B[K,N] (+bias)(+relu), fp32 accum.
// A_WS: A is a ws buffer (always bf16). B and bias are harness inputs (flag dtype).
// 64x64 tile, 16x16 threads, 4x4 per thread.
template<bool A_WS, bool RELU, bool BIAS>
__global__ __launch_bounds__(256) void gemm_kernel(const void* __restrict__ A,
    const void* __restrict__ Bw, const void* __restrict__ bias,
    bf16* __restrict__ C, int M, int N, int K, const int* __restrict__ flagp)
{
    const bool inF32 = (*flagp) != 0;
    const bool aF32  = A_WS ? false : inF32;

    __shared__ float sA[16][64];
    __shared__ float sB[16][64];
    const int tx = threadIdx.x, ty = threadIdx.y;
    const int t  = ty * 16 + tx;               // 0..255
    const int row0 = blockIdx.y * 64;
    const int col0 = blockIdx.x * 64;

    float acc[4][4] = {};

    const int mA = (4 * t) >> 4;               // A-tile: 4 consecutive k for one m
    const int kA = (4 * t) & 15;               // multiple of 4
    const int kB = (4 * t) >> 6;               // B-tile: 4 consecutive n for one k
    const int nB = (4 * t) & 63;               // multiple of 4

    for (int k0 = 0; k0 < K; k0 += 16) {
        const F4 av = ld4(A, (size_t)(row0 + mA) * K + k0 + kA, aF32);
        sA[kA + 0][mA] = av.x;
        sA[kA + 1][mA] = av.y;
        sA[kA + 2][mA] = av.z;
        sA[kA + 3][mA] = av.w;
        const F4 bv = ld4(Bw, (size_t)(k0 + kB) * N + col0 + nB, inF32);
        sB[kB][nB + 0] = bv.x;
        sB[kB][nB + 1] = bv.y;
        sB[kB][nB + 2] = bv.z;
        sB[kB][nB + 3] = bv.w;
        __syncthreads();
        #pragma unroll
        for (int k = 0; k < 16; ++k) {
            float a[4], bb[4];
            #pragma unroll
            for (int i = 0; i < 4; ++i) a[i]  = sA[k][ty * 4 + i];
            #pragma unroll
            for (int j = 0; j < 4; ++j) bb[j] = sB[k][tx * 4 + j];
            #pragma unroll
            for (int i = 0; i < 4; ++i)
                #pragma unroll
                for (int j = 0; j < 4; ++j) acc[i][j] += a[i] * bb[j];
        }
        __syncthreads();
    }

    #pragma unroll
    for (int i = 0; i < 4; ++i) {
        const int r = row0 + ty * 4 + i;
        #pragma unroll
        for (int j = 0; j < 4; ++j) {
            const int c = col0 + tx * 4 + j;
            float v = acc[i][j];
            if (BIAS) v += ld1(bias, c, inF32);
            if (RELU) v = v > 0.f ? v : 0.f;
            C[(size_t)r * N + c] = __float2bfloat16(v);
        }
    }
}

// One block per (b, h, q_row). All tensors are ws bf16. Scores in LDS.
__global__ __launch_bounds__(256) void attn_kernel(const bf16* __restrict__ Q,
    const bf16* __restrict__ Km, const bf16* __restrict__ Vm,
    const int* __restrict__ mask, bf16* __restrict__ ctx)
{
    __shared__ float qv[DK];
    __shared__ float sc[SEQ];
    __shared__ float red[256];
    __shared__ float part[4][DK];

    const int tid = threadIdx.x;
    const int idx = blockIdx.x;
    const int qs  = idx & (SEQ - 1);
    const int bh  = idx >> 11;
    const int h   = bh & (N_HEADS - 1);
    const int b   = bh >> 4;

    const size_t qoff = ((size_t)(b * SEQ + qs)) * D_MODEL + h * DK;
    if (tid < DK) qv[tid] = toF(Q[qoff + tid]);
    __syncthreads();

    float lmax = -1e30f;
    for (int j = tid; j < SEQ; j += 256) {
        const ushort4* kr = reinterpret_cast<const ushort4*>(Km + ((size_t)(b * SEQ + j)) * D_MODEL + h * DK);
        float dot = 0.f;
        #pragma unroll
        for (int d4 = 0; d4 < DK / 4; ++d4) {
            const ushort4 kv = kr[d4];
            dot += qv[4*d4 + 0] * bf2f(kv.x) + qv[4*d4 + 1] * bf2f(kv.y)
                 + qv[4*d4 + 2] * bf2f(kv.z) + qv[4*d4 + 3] * bf2f(kv.w);
        }
        float s = dot * 0.125f;                      // 1/sqrt(64)
        if (mask[b * SEQ + j] == 0) s = -1e9f;
        sc[j] = s;
        lmax = fmaxf(lmax, s);
    }
    red[tid] = lmax; __syncthreads();
    for (int s = 128; s > 0; s >>= 1) { if (tid < s) red[tid] = fmaxf(red[tid], red[tid + s]); __syncthreads(); }
    const float m = red[0]; __syncthreads();

    float lsum = 0.f;
    for (int j = tid; j < SEQ; j += 256) { float p = __expf(sc[j] - m); sc[j] = p; lsum += p; }
    red[tid] = lsum; __syncthreads();
    for (int s = 128; s > 0; s >>= 1) { if (tid < s) red[tid] += red[tid + s]; __syncthreads(); }
    const float linv = 1.f / red[0];
    __syncthreads();

    const int d  = tid & 63;
    const int p4 = tid >> 6;
    float acc = 0.f;
    for (int j = p4 * 512; j < (p4 + 1) * 512; ++j)
        acc += sc[j] * toF(Vm[((size_t)(b * SEQ + j)) * D_MODEL + h * DK + d]);
    part[p4][d] = acc; __syncthreads();
    if (tid < DK)
        ctx[qoff + tid] = __float2bfloat16(
            (part[0][tid] + part[1][tid] + part[2][tid] + part[3][tid]) * linv);
}

// y = alpha*(v-mean)/(std+eps)+bias, v = base + add. add is always ws bf16.
// BASE_WS: base is ws bf16 (else flag dtype). OUT_WS: out is ws bf16 (else flag dtype).
template<bool BASE_WS, bool OUT_WS>
__global__ __launch_bounds__(256) void ln_kernel(const void* __restrict__ base,
    const bf16* __restrict__ addv, const void* __restrict__ alpha,
    const void* __restrict__ bias, void* __restrict__ outp, const int* __restrict__ flagp)
{
    const bool inF32 = (*flagp) != 0;
    __shared__ float vals[D_MODEL];
    __shared__ float red[256];
    const int row = blockIdx.x, tid = threadIdx.x;

    float lsum = 0.f;
    for (int i = tid; i < D_MODEL; i += 256) {
        const size_t off = (size_t)row * D_MODEL + i;
        float v = (BASE_WS ? toF(((const bf16*)base)[off]) : ld1(base, off, inF32)) + toF(addv[off]);
        vals[i] = v; lsum += v;
    }
    red[tid] = lsum; __syncthreads();
    for (int s = 128; s > 0; s >>= 1) { if (tid < s) red[tid] += red[tid + s]; __syncthreads(); }
    const float mean = red[0] / (float)D_MODEL; __syncthreads();

    float lsq = 0.f;
    for (int i = tid; i < D_MODEL; i += 256) { float dd = vals[i] - mean; lsq += dd * dd; }
    red[tid] = lsq; __syncthreads();
    for (int s = 128; s > 0; s >>= 1) { if (tid < s) red[tid] += red[tid + s]; __syncthreads(); }
    const float var = red[0] / (float)(D_MODEL - 1);
    const float inv = 1.f / (sqrtf(var) + LN_EPS);

    for (int i = tid; i < D_MODEL; i += 256) {
        const size_t off = (size_t)row * D_MODEL + i;
        const float y = ld1(alpha, i, inF32) * (vals[i] - mean) * inv + ld1(bias, i, inF32);
        if (OUT_WS || !inF32) ((bf16*)outp)[off] = __float2bfloat16(y);
        else                  ((float*)outp)[off] = y;
    }
}

extern "C" void kernel_launch(void* const* d_in, const int* in_sizes, int n_in,
                              void* d_out, int out_size, void* d_ws, size_t ws_size,
                              hipStream_t stream)
{
    const void* x    = d_in[0];
    const int*  mask = (const int*)d_in[1];
    const void* wq   = d_in[2];
    const void* wk   = d_in[3];
    const void* wv   = d_in[4];
    const void* wo   = d_in[5];
    const void* wo_b = d_in[6];
    const void* w1   = d_in[7];
    const void* b1   = d_in[8];
    const void* w2   = d_in[9];
    const void* b2   = d_in[10];
    const void* al1  = d_in[11];
    const void* bi1  = d_in[12];
    const void* al2  = d_in[13];
    const void* bi2  = d_in[14];

    // ws layout (all intermediates canonical bf16):
    // [0,8) Qb  [8,16) Kb  [16,24) Vb  [24,32) CTXb  [32,40) X1b  [40,48) X2b
    // FFb (16M elems, 32MB) overlays [0,32) after Q/K/V/CTX are dead.
    // [48MB] int dtype flag.
    const size_t MB = 1024 * 1024;
    if (ws_size < 48 * MB + 4096) return;   // loud failure: out stays 0 -> absmax 5.1875

    char* ws = (char*)d_ws;
    bf16* Qb    = (bf16*)(ws + 0 * MB);
    bf16* Kb    = (bf16*)(ws + 8 * MB);
    bf16* Vb    = (bf16*)(ws + 16 * MB);
    bf16* CTXb  = (bf16*)(ws + 24 * MB);
    bf16* X1b   = (bf16*)(ws + 32 * MB);
    bf16* X2b   = (bf16*)(ws + 40 * MB);
    bf16* FFb   = (bf16*)(ws + 0 * MB);
    int*  flagp = (int*)(ws + 48 * MB);

    probe_kernel<<<1, 256, 0, stream>>>(x, flagp);

    dim3 blk(16, 16);
    dim3 gD(D_MODEL / 64, ROWS / 64);                // 16 x 64
    dim3 gF(D_FF / 64, ROWS / 64);                   // 64 x 64

    gemm_kernel<false, false, false><<<gD, blk, 0, stream>>>(x, wq, nullptr, Qb, ROWS, D_MODEL, D_MODEL, flagp);
    gemm_kernel<false, false, false><<<gD, blk, 0, stream>>>(x, wk, nullptr, Kb, ROWS, D_MODEL, D_MODEL, flagp);
    gemm_kernel<false, false, false><<<gD, blk, 0, stream>>>(x, wv, nullptr, Vb, ROWS, D_MODEL, D_MODEL, flagp);

    attn_kernel<<<dim3(BATCH * N_HEADS * SEQ), 256, 0, stream>>>(Qb, Kb, Vb, mask, CTXb);

    // attn_out = CTX @ wo + wo_b  -> X2b
    gemm_kernel<true, false, true><<<gD, blk, 0, stream>>>(CTXb, wo, wo_b, X2b, ROWS, D_MODEL, D_MODEL, flagp);

    // x1 = LN(x + attn_out) -> X1b
    ln_kernel<false, true><<<ROWS, 256, 0, stream>>>(x, X2b, al1, bi1, X1b, flagp);

    // ff = relu(x1 @ w1 + b1) -> FFb
    gemm_kernel<true, true, true><<<gF, blk, 0, stream>>>(X1b, w1, b1, FFb, ROWS, D_FF, D_MODEL, flagp);

    // x2 = ff @ w2 + b2 -> X2b
    gemm_kernel<true, false, true><<<gD, blk, 0, stream>>>(FFb, w2, b2, X2b, ROWS, D_MODEL, D_FF, flagp);

    // out = LN(x1 + x2) -> d_out (flag dtype)
    ln_kernel<true, false><<<ROWS, 256, 0, stream>>>(X1b, X2b, al2, bi2, d_out, flagp);
}

// Round 4
// 2124.773 us; speedup vs baseline: 2.8148x; 2.8148x over previous
//
#include <hip/hip_runtime.h>
#include <hip/hip_bf16.h>

#define D_MODEL 1024
#define N_HEADS 16
#define DK      64
#define SEQ     2048
#define BATCH   2
#define D_FF    4096
#define ROWS    (BATCH*SEQ)   // 4096
#define LN_EPS  1e-6f

typedef __hip_bfloat16 bf16;

__device__ inline float bf2f(unsigned short u){ return __uint_as_float(((unsigned)u) << 16); }
__device__ inline float toF(bf16 v){ return __bfloat162float(v); }
__device__ inline unsigned short f2bu(float f){ bf16 h = __float2bfloat16(f); return *reinterpret_cast<unsigned short*>(&h); }

struct F4 { float x, y, z, w; };

__device__ inline F4 ld4(const void* p, size_t idx, bool f32) {
    F4 r;
    if (f32) {
        const float4 v = *reinterpret_cast<const float4*>((const float*)p + idx);
        r.x = v.x; r.y = v.y; r.z = v.z; r.w = v.w;
    } else {
        const ushort4 v = *reinterpret_cast<const ushort4*>((const bf16*)p + idx);
        r.x = bf2f(v.x); r.y = bf2f(v.y); r.z = bf2f(v.z); r.w = bf2f(v.w);
    }
    return r;
}
__device__ inline float ld1(const void* p, size_t idx, bool f32) {
    return f32 ? ((const float*)p)[idx] : toF(((const bf16*)p)[idx]);
}

// Dtype probe: scan first 8192 elems of x as bf16; fp32 bits misread as bf16
// produce Inf/NaN/huge values with overwhelming probability.
__global__ void probe_kernel(const void* __restrict__ xp, int* __restrict__ flag) {
    __shared__ int hit;
    if (threadIdx.x == 0) hit = 0;
    __syncthreads();
    const bf16* p = (const bf16*)xp;
    int bad = 0;
    for (int i = threadIdx.x; i < 8192; i += 256) {
        float v = fabsf(toF(p[i]));
        if (!(v <= 1e5f)) bad = 1;
    }
    if (bad) atomicOr(&hit, 1);
    __syncthreads();
    if (threadIdx.x == 0) *flag = hit;   // 1 => inputs are fp32
}

// C[M,N] (bf16 ws) = A[M,K] @ B[K,N] (+bias)(+relu), fp32 accum. 64x64 tile.
template<bool A_WS, bool RELU, bool BIAS>
__global__ __launch_bounds__(256) void gemm_kernel(const void* __restrict__ A,
    const void* __restrict__ Bw, const void* __restrict__ bias,
    bf16* __restrict__ C, int M, int N, int K, const int* __restrict__ flagp)
{
    const bool inF32 = (*flagp) != 0;
    const bool aF32  = A_WS ? false : inF32;

    __shared__ float sA[16][64];
    __shared__ float sB[16][64];
    const int tx = threadIdx.x, ty = threadIdx.y;
    const int t  = ty * 16 + tx;
    const int row0 = blockIdx.y * 64;
    const int col0 = blockIdx.x * 64;

    float acc[4][4] = {};

    const int mA = (4 * t) >> 4;
    const int kA = (4 * t) & 15;
    const int kB = (4 * t) >> 6;
    const int nB = (4 * t) & 63;

    for (int k0 = 0; k0 < K; k0 += 16) {
        const F4 av = ld4(A, (size_t)(row0 + mA) * K + k0 + kA, aF32);
        sA[kA + 0][mA] = av.x;
        sA[kA + 1][mA] = av.y;
        sA[kA + 2][mA] = av.z;
        sA[kA + 3][mA] = av.w;
        const F4 bv = ld4(Bw, (size_t)(k0 + kB) * N + col0 + nB, inF32);
        sB[kB][nB + 0] = bv.x;
        sB[kB][nB + 1] = bv.y;
        sB[kB][nB + 2] = bv.z;
        sB[kB][nB + 3] = bv.w;
        __syncthreads();
        #pragma unroll
        for (int k = 0; k < 16; ++k) {
            float a[4], bb[4];
            #pragma unroll
            for (int i = 0; i < 4; ++i) a[i]  = sA[k][ty * 4 + i];
            #pragma unroll
            for (int j = 0; j < 4; ++j) bb[j] = sB[k][tx * 4 + j];
            #pragma unroll
            for (int i = 0; i < 4; ++i)
                #pragma unroll
                for (int j = 0; j < 4; ++j) acc[i][j] += a[i] * bb[j];
        }
        __syncthreads();
    }

    #pragma unroll
    for (int i = 0; i < 4; ++i) {
        const int r = row0 + ty * 4 + i;
        #pragma unroll
        for (int j = 0; j < 4; ++j) {
            const int c = col0 + tx * 4 + j;
            float v = acc[i][j];
            if (BIAS) v += ld1(bias, c, inF32);
            if (RELU) v = v > 0.f ? v : 0.f;
            C[(size_t)r * N + c] = __float2bfloat16(v);
        }
    }
}

// Flash attention: one block = (b, h, 64 q-rows). 256 threads.
// Thread (tq = t>>4, tk = t&15): S rows r=4tq+j, cols kk=tk+16i; O dims d=4tk+0..3.
// LDS: Qs fp32 (scaled, stride 68), Ps fp32 (stride 68), Ks/Vs raw bf16 (stride 68).
__global__ __launch_bounds__(256) void fattn_kernel(
    const bf16* __restrict__ Qg, const bf16* __restrict__ Kg,
    const bf16* __restrict__ Vg, const int* __restrict__ mask,
    bf16* __restrict__ ctx)
{
    __shared__ float Qs[64 * 68];
    __shared__ float Ps[64 * 68];
    __shared__ unsigned short KsH[64 * 68];
    __shared__ unsigned short VsH[64 * 68];

    const int t   = threadIdx.x;
    const int idx = blockIdx.x;
    const int qt  = idx & 31;
    const int h   = (idx >> 5) & 15;
    const int b   = idx >> 9;
    const int q0  = qt * 64;

    const int tq  = t >> 4;
    const int tk  = t & 15;
    const int sr  = t >> 2;          // staging row
    const int sd0 = (t & 3) * 16;    // staging col base

    // ---- stage Q, pre-scaled by 1/sqrt(dk)=0.125 ----
    {
        const uint4* src = reinterpret_cast<const uint4*>(
            Qg + ((size_t)(b * SEQ + q0 + sr)) * D_MODEL + h * DK + sd0);
        #pragma unroll
        for (int u = 0; u < 2; ++u) {
            uint4 w = src[u];
            float* q = &Qs[sr * 68 + sd0 + 8 * u];
            q[0] = __uint_as_float(w.x << 16)         * 0.125f;
            q[1] = __uint_as_float(w.x & 0xffff0000u) * 0.125f;
            q[2] = __uint_as_float(w.y << 16)         * 0.125f;
            q[3] = __uint_as_float(w.y & 0xffff0000u) * 0.125f;
            q[4] = __uint_as_float(w.z << 16)         * 0.125f;
            q[5] = __uint_as_float(w.z & 0xffff0000u) * 0.125f;
            q[6] = __uint_as_float(w.w << 16)         * 0.125f;
            q[7] = __uint_as_float(w.w & 0xffff0000u) * 0.125f;
        }
    }

    float4 o[4];
    float m_r[4], l_r[4];
    #pragma unroll
    for (int j = 0; j < 4; ++j) {
        o[j] = make_float4(0.f, 0.f, 0.f, 0.f);
        m_r[j] = -1e30f; l_r[j] = 0.f;
    }

    for (int kt = 0; kt < SEQ / 64; ++kt) {
        const int k0 = kt * 64;
        if (kt) __syncthreads();                  // protect Ks/Vs from overwrite
        // ---- stage K,V (raw bf16 copy) ----
        {
            const size_t rowoff = ((size_t)(b * SEQ + k0 + sr)) * D_MODEL + h * DK + sd0;
            const ushort4* ks = reinterpret_cast<const ushort4*>(Kg + rowoff);
            const ushort4* vs = reinterpret_cast<const ushort4*>(Vg + rowoff);
            #pragma unroll
            for (int u = 0; u < 4; ++u) {
                *reinterpret_cast<ushort4*>(&KsH[sr * 68 + sd0 + 4 * u]) = ks[u];
                *reinterpret_cast<ushort4*>(&VsH[sr * 68 + sd0 + 4 * u]) = vs[u];
            }
        }
        __syncthreads();

        // ---- S = (Q*scale) @ K^T ----
        float s[4][4];
        #pragma unroll
        for (int j = 0; j < 4; ++j)
            #pragma unroll
            for (int i = 0; i < 4; ++i) s[j][i] = 0.f;

        for (int d0 = 0; d0 < 64; d0 += 4) {
            float4 q4[4], k4[4];
            #pragma unroll
            for (int j = 0; j < 4; ++j)
                q4[j] = *reinterpret_cast<const float4*>(&Qs[(4 * tq + j) * 68 + d0]);
            #pragma unroll
            for (int i = 0; i < 4; ++i) {
                ushort4 kr = *reinterpret_cast<const ushort4*>(&KsH[(tk + 16 * i) * 68 + d0]);
                k4[i].x = bf2f(kr.x); k4[i].y = bf2f(kr.y);
                k4[i].z = bf2f(kr.z); k4[i].w = bf2f(kr.w);
            }
            #pragma unroll
            for (int j = 0; j < 4; ++j)
                #pragma unroll
                for (int i = 0; i < 4; ++i)
                    s[j][i] += q4[j].x * k4[i].x + q4[j].y * k4[i].y
                             + q4[j].z * k4[i].z + q4[j].w * k4[i].w;
        }

        // ---- mask ----
        int mk[4];
        #pragma unroll
        for (int i = 0; i < 4; ++i) mk[i] = mask[b * SEQ + k0 + tk + 16 * i];
        #pragma unroll
        for (int j = 0; j < 4; ++j)
            #pragma unroll
            for (int i = 0; i < 4; ++i)
                if (mk[i] == 0) s[j][i] = -1e9f;

        // ---- online softmax (rows spread over 16 lanes sharing tq) ----
        #pragma unroll
        for (int j = 0; j < 4; ++j) {
            float mx = fmaxf(fmaxf(s[j][0], s[j][1]), fmaxf(s[j][2], s[j][3]));
            #pragma unroll
            for (int off = 1; off < 16; off <<= 1) mx = fmaxf(mx, __shfl_xor(mx, off));
            const float mn = fmaxf(m_r[j], mx);
            const float alpha = __expf(m_r[j] - mn);
            float p[4], psum = 0.f;
            #pragma unroll
            for (int i = 0; i < 4; ++i) { p[i] = __expf(s[j][i] - mn); psum += p[i]; }
            #pragma unroll
            for (int off = 1; off < 16; off <<= 1) psum += __shfl_xor(psum, off);
            l_r[j] = l_r[j] * alpha + psum;
            m_r[j] = mn;
            o[j].x *= alpha; o[j].y *= alpha; o[j].z *= alpha; o[j].w *= alpha;
            #pragma unroll
            for (int i = 0; i < 4; ++i)
                Ps[(4 * tq + j) * 68 + tk + 16 * i] = p[i];
        }
        __syncthreads();

        // ---- O += P @ V ----
        for (int kk0 = 0; kk0 < 64; kk0 += 4) {
            float4 v4[4];
            #pragma unroll
            for (int u = 0; u < 4; ++u) {
                ushort4 vr = *reinterpret_cast<const ushort4*>(&VsH[(kk0 + u) * 68 + 4 * tk]);
                v4[u].x = bf2f(vr.x); v4[u].y = bf2f(vr.y);
                v4[u].z = bf2f(vr.z); v4[u].w = bf2f(vr.w);
            }
            #pragma unroll
            for (int j = 0; j < 4; ++j) {
                float4 p4 = *reinterpret_cast<const float4*>(&Ps[(4 * tq + j) * 68 + kk0]);
                o[j].x += p4.x * v4[0].x + p4.y * v4[1].x + p4.z * v4[2].x + p4.w * v4[3].x;
                o[j].y += p4.x * v4[0].y + p4.y * v4[1].y + p4.z * v4[2].y + p4.w * v4[3].y;
                o[j].z += p4.x * v4[0].z + p4.y * v4[1].z + p4.z * v4[2].z + p4.w * v4[3].z;
                o[j].w += p4.x * v4[0].w + p4.y * v4[1].w + p4.z * v4[2].w + p4.w * v4[3].w;
            }
        }
    }

    // ---- normalize + store ----
    #pragma unroll
    for (int j = 0; j < 4; ++j) {
        const float inv = 1.f / l_r[j];
        bf16* dst = ctx + ((size_t)(b * SEQ + q0 + 4 * tq + j)) * D_MODEL + h * DK + 4 * tk;
        ushort4 pk;
        pk.x = f2bu(o[j].x * inv);
        pk.y = f2bu(o[j].y * inv);
        pk.z = f2bu(o[j].z * inv);
        pk.w = f2bu(o[j].w * inv);
        *reinterpret_cast<ushort4*>(dst) = pk;
    }
}

// y = alpha*(v-mean)/(std+eps)+bias, v = base + add (add always ws bf16), ddof=1.
template<bool BASE_WS, bool OUT_WS>
__global__ __launch_bounds__(256) void ln_kernel(const void* __restrict__ base,
    const bf16* __restrict__ addv, const void* __restrict__ alpha,
    const void* __restrict__ bias, void* __restrict__ outp, const int* __restrict__ flagp)
{
    const bool inF32 = (*flagp) != 0;
    __shared__ float vals[D_MODEL];
    __shared__ float red[256];
    const int row = blockIdx.x, tid = threadIdx.x;

    float lsum = 0.f;
    for (int i = tid; i < D_MODEL; i += 256) {
        const size_t off = (size_t)row * D_MODEL + i;
        float v = (BASE_WS ? toF(((const bf16*)base)[off]) : ld1(base, off, inF32)) + toF(addv[off]);
        vals[i] = v; lsum += v;
    }
    red[tid] = lsum; __syncthreads();
    for (int s = 128; s > 0; s >>= 1) { if (tid < s) red[tid] += red[tid + s]; __syncthreads(); }
    const float mean = red[0] / (float)D_MODEL; __syncthreads();

    float lsq = 0.f;
    for (int i = tid; i < D_MODEL; i += 256) { float dd = vals[i] - mean; lsq += dd * dd; }
    red[tid] = lsq; __syncthreads();
    for (int s = 128; s > 0; s >>= 1) { if (tid < s) red[tid] += red[tid + s]; __syncthreads(); }
    const float var = red[0] / (float)(D_MODEL - 1);
    const float inv = 1.f / (sqrtf(var) + LN_EPS);

    for (int i = tid; i < D_MODEL; i += 256) {
        const size_t off = (size_t)row * D_MODEL + i;
        const float y = ld1(alpha, i, inF32) * (vals[i] - mean) * inv + ld1(bias, i, inF32);
        if (OUT_WS || !inF32) ((bf16*)outp)[off] = __float2bfloat16(y);
        else                  ((float*)outp)[off] = y;
    }
}

extern "C" void kernel_launch(void* const* d_in, const int* in_sizes, int n_in,
                              void* d_out, int out_size, void* d_ws, size_t ws_size,
                              hipStream_t stream)
{
    const void* x    = d_in[0];
    const int*  mask = (const int*)d_in[1];
    const void* wq   = d_in[2];
    const void* wk   = d_in[3];
    const void* wv   = d_in[4];
    const void* wo   = d_in[5];
    const void* wo_b = d_in[6];
    const void* w1   = d_in[7];
    const void* b1   = d_in[8];
    const void* w2   = d_in[9];
    const void* b2   = d_in[10];
    const void* al1  = d_in[11];
    const void* bi1  = d_in[12];
    const void* al2  = d_in[13];
    const void* bi2  = d_in[14];

    const size_t MB = 1024 * 1024;
    if (ws_size < 48 * MB + 4096) return;

    char* ws = (char*)d_ws;
    bf16* Qb    = (bf16*)(ws + 0 * MB);
    bf16* Kb    = (bf16*)(ws + 8 * MB);
    bf16* Vb    = (bf16*)(ws + 16 * MB);
    bf16* CTXb  = (bf16*)(ws + 24 * MB);
    bf16* X1b   = (bf16*)(ws + 32 * MB);
    bf16* X2b   = (bf16*)(ws + 40 * MB);
    bf16* FFb   = (bf16*)(ws + 0 * MB);    // overlays Q/K/V/CTX after attention
    int*  flagp = (int*)(ws + 48 * MB);

    probe_kernel<<<1, 256, 0, stream>>>(x, flagp);

    dim3 blk(16, 16);
    dim3 gD(D_MODEL / 64, ROWS / 64);
    dim3 gF(D_FF / 64, ROWS / 64);

    gemm_kernel<false, false, false><<<gD, blk, 0, stream>>>(x, wq, nullptr, Qb, ROWS, D_MODEL, D_MODEL, flagp);
    gemm_kernel<false, false, false><<<gD, blk, 0, stream>>>(x, wk, nullptr, Kb, ROWS, D_MODEL, D_MODEL, flagp);
    gemm_kernel<false, false, false><<<gD, blk, 0, stream>>>(x, wv, nullptr, Vb, ROWS, D_MODEL, D_MODEL, flagp);

    fattn_kernel<<<dim3(BATCH * N_HEADS * (SEQ / 64)), 256, 0, stream>>>(Qb, Kb, Vb, mask, CTXb);

    gemm_kernel<true, false, true><<<gD, blk, 0, stream>>>(CTXb, wo, wo_b, X2b, ROWS, D_MODEL, D_MODEL, flagp);

    ln_kernel<false, true><<<ROWS, 256, 0, stream>>>(x, X2b, al1, bi1, X1b, flagp);

    gemm_kernel<true, true, true><<<gF, blk, 0, stream>>>(X1b, w1, b1, FFb, ROWS, D_FF, D_MODEL, flagp);

    gemm_kernel<true, false, true><<<gD, blk, 0, stream>>>(FFb, w2, b2, X2b, ROWS, D_MODEL, D_FF, flagp);

    ln_kernel<true, false><<<ROWS, 256, 0, stream>>>(X1b, X2b, al2, bi2, d_out, flagp);
}

// Round 5
// 941.485 us; speedup vs baseline: 6.3525x; 2.2568x over previous
//
#include <hip/hip_runtime.h>
#include <hip/hip_bf16.h>

#define D_MODEL 1024
#define N_HEADS 16
#define DK      64
#define SEQ     2048
#define BATCH   2
#define D_FF    4096
#define ROWS    (BATCH*SEQ)   // 4096
#define LN_EPS  1e-6f
#define SSTR    72            // LDS tile row stride (bf16 elems): 64 data + 8 pad, 144B (16B-aligned)

typedef __hip_bfloat16 bf16;
typedef __attribute__((ext_vector_type(8))) short frag8;   // 8 bf16 = 4 VGPRs (MFMA A/B)
typedef __attribute__((ext_vector_type(4))) float facc4;   // 4 f32 (MFMA C/D)

__device__ inline float bf2f(unsigned short u){ return __uint_as_float(((unsigned)u) << 16); }
__device__ inline float toF(bf16 v){ return __bfloat162float(v); }
__device__ inline unsigned short f2bu(float f){ bf16 h = __float2bfloat16(f); return *reinterpret_cast<unsigned short*>(&h); }

__device__ inline float ld1(const void* p, size_t idx, bool f32) {
    return f32 ? ((const float*)p)[idx] : toF(((const bf16*)p)[idx]);
}

struct U8 { unsigned short v[8]; };
// 8 consecutive elements at idx (16B-aligned) as bf16 bits.
__device__ inline U8 ld8bf(const void* p, size_t idx, bool f32) {
    U8 r;
    if (!f32) {
        *reinterpret_cast<uint4*>(r.v) = *reinterpret_cast<const uint4*>((const unsigned short*)p + idx);
    } else {
        const float* f = (const float*)p + idx;
        const float4 a = *reinterpret_cast<const float4*>(f);
        const float4 b = *reinterpret_cast<const float4*>(f + 4);
        r.v[0]=f2bu(a.x); r.v[1]=f2bu(a.y); r.v[2]=f2bu(a.z); r.v[3]=f2bu(a.w);
        r.v[4]=f2bu(b.x); r.v[5]=f2bu(b.y); r.v[6]=f2bu(b.z); r.v[7]=f2bu(b.w);
    }
    return r;
}

// Dtype probe: fp32 bits misread as bf16 give Inf/NaN/huge values.
__global__ void probe_kernel(const void* __restrict__ xp, int* __restrict__ flag) {
    __shared__ int hit;
    if (threadIdx.x == 0) hit = 0;
    __syncthreads();
    const bf16* p = (const bf16*)xp;
    int bad = 0;
    for (int i = threadIdx.x; i < 8192; i += 256) {
        float v = fabsf(toF(p[i]));
        if (!(v <= 1e5f)) bad = 1;
    }
    if (bad) atomicOr(&hit, 1);
    __syncthreads();
    if (threadIdx.x == 0) *flag = hit;   // 1 => inputs are fp32
}

// WT[n][k] = W[k][n], output bf16. grid (N/32, K/32), block (32,8).
__global__ __launch_bounds__(256) void transpose_kernel(const void* __restrict__ W,
    bf16* __restrict__ WT, int K, int N, const int* __restrict__ flagp)
{
    const bool f32 = (*flagp) != 0;
    __shared__ float tile[32][33];
    const int tx = threadIdx.x, ty = threadIdx.y;
    const int n0 = blockIdx.x * 32, k0 = blockIdx.y * 32;
    #pragma unroll
    for (int r = 0; r < 4; ++r)
        tile[ty + 8*r][tx] = ld1(W, (size_t)(k0 + ty + 8*r) * N + n0 + tx, f32);
    __syncthreads();
    #pragma unroll
    for (int r = 0; r < 4; ++r)
        WT[(size_t)(n0 + ty + 8*r) * K + k0 + tx] = __float2bfloat16(tile[tx][ty + 8*r]);
}

// MFMA GEMM: C[M,N] bf16 = A[M,K] @ BT[N,K]^T (+bias)(+relu), fp32 accum.
// 128x128 tile, 4 waves (each 64x64 = 4x4 MFMA 16x16x32 tiles), BK=64.
// NMAT>1: fused QKV — blockIdx.x selects weight/output matrix (N must be 1024).
template<bool A_F, bool RELU, bool BIAS, int NMAT>
__global__ __launch_bounds__(256) void mgemm_kernel(const void* __restrict__ A,
    const bf16* __restrict__ BT, const void* __restrict__ bias,
    bf16* __restrict__ C, int M, int N, int K, const int* __restrict__ flagp)
{
    const bool inF32 = (*flagp) != 0;
    const bool aF32  = A_F ? inF32 : false;

    __shared__ unsigned short sA[128 * SSTR];
    __shared__ unsigned short sB[128 * SSTR];

    int which = 0, colb = blockIdx.x;
    if (NMAT > 1) { which = blockIdx.x >> 3; colb = blockIdx.x & 7; }   // N==1024
    const bf16* Bp = BT + (size_t)which * N * K;
    bf16*       Cp = C  + (size_t)which * M * N;

    const int row0 = blockIdx.y * 128;
    const int col0 = colb * 128;

    const int t    = threadIdx.x;
    const int wave = t >> 6;
    const int lane = t & 63;
    const int lm   = lane & 15;
    const int q    = lane >> 4;
    const int wm   = (wave & 1) * 64;
    const int wn   = (wave >> 1) * 64;

    facc4 acc[4][4];
    #pragma unroll
    for (int i = 0; i < 4; ++i)
        #pragma unroll
        for (int j = 0; j < 4; ++j)
            acc[i][j] = (facc4){0.f, 0.f, 0.f, 0.f};

    for (int k0 = 0; k0 < K; k0 += 64) {
        if (k0) __syncthreads();
        // Stage A-tile (128 rows x 64 k) and BT-tile (128 n-rows x 64 k).
        // Chunk ci = u*256 + t: row = ci>>3, kchunk = ci&7 -> coalesced 16B loads,
        // conflict-free ds_write_b128 (stride-72 rows are bank-balanced).
        #pragma unroll
        for (int u = 0; u < 4; ++u) {
            const int ci = u * 256 + t;
            const int r = ci >> 3, c = ci & 7;
            U8 d = ld8bf(A, (size_t)(row0 + r) * K + k0 + 8 * c, aF32);
            *reinterpret_cast<uint4*>(&sA[r * SSTR + 8 * c]) = *reinterpret_cast<const uint4*>(d.v);
            U8 e = ld8bf(Bp, (size_t)(col0 + r) * K + k0 + 8 * c, false);
            *reinterpret_cast<uint4*>(&sB[r * SSTR + 8 * c]) = *reinterpret_cast<const uint4*>(e.v);
        }
        __syncthreads();

        #pragma unroll
        for (int kk = 0; kk < 64; kk += 32) {
            frag8 af[4], bfr[4];
            #pragma unroll
            for (int im = 0; im < 4; ++im)
                af[im] = *reinterpret_cast<const frag8*>(&sA[(wm + 16*im + lm) * SSTR + kk + 8*q]);
            #pragma unroll
            for (int in = 0; in < 4; ++in)
                bfr[in] = *reinterpret_cast<const frag8*>(&sB[(wn + 16*in + lm) * SSTR + kk + 8*q]);
            #pragma unroll
            for (int im = 0; im < 4; ++im)
                #pragma unroll
                for (int in = 0; in < 4; ++in)
                    acc[im][in] = __builtin_amdgcn_mfma_f32_16x16x32_bf16(af[im], bfr[in], acc[im][in], 0, 0, 0);
        }
    }

    // Epilogue: C/D layout col=lane&15, row=quad*4+reg.
    #pragma unroll
    for (int in = 0; in < 4; ++in) {
        const int col = col0 + wn + 16*in + lm;
        float bv = 0.f;
        if (BIAS) bv = ld1(bias, col, inF32);
        #pragma unroll
        for (int im = 0; im < 4; ++im) {
            #pragma unroll
            for (int r = 0; r < 4; ++r) {
                const int row = row0 + wm + 16*im + 4*q + r;
                float v = acc[im][in][r] + bv;
                if (RELU) v = fmaxf(v, 0.f);
                Cp[(size_t)row * N + col] = __float2bfloat16(v);
            }
        }
    }
}

// Flash attention: one block = (b, h, 64 q-rows). 256 threads. (unchanged from R4)
__global__ __launch_bounds__(256) void fattn_kernel(
    const bf16* __restrict__ Qg, const bf16* __restrict__ Kg,
    const bf16* __restrict__ Vg, const int* __restrict__ mask,
    bf16* __restrict__ ctx)
{
    __shared__ float Qs[64 * 68];
    __shared__ float Ps[64 * 68];
    __shared__ unsigned short KsH[64 * 68];
    __shared__ unsigned short VsH[64 * 68];

    const int t   = threadIdx.x;
    const int idx = blockIdx.x;
    const int qt  = idx & 31;
    const int h   = (idx >> 5) & 15;
    const int b   = idx >> 9;
    const int q0  = qt * 64;

    const int tq  = t >> 4;
    const int tk  = t & 15;
    const int sr  = t >> 2;
    const int sd0 = (t & 3) * 16;

    {
        const uint4* src = reinterpret_cast<const uint4*>(
            Qg + ((size_t)(b * SEQ + q0 + sr)) * D_MODEL + h * DK + sd0);
        #pragma unroll
        for (int u = 0; u < 2; ++u) {
            uint4 w = src[u];
            float* qp = &Qs[sr * 68 + sd0 + 8 * u];
            qp[0] = __uint_as_float(w.x << 16)         * 0.125f;
            qp[1] = __uint_as_float(w.x & 0xffff0000u) * 0.125f;
            qp[2] = __uint_as_float(w.y << 16)         * 0.125f;
            qp[3] = __uint_as_float(w.y & 0xffff0000u) * 0.125f;
            qp[4] = __uint_as_float(w.z << 16)         * 0.125f;
            qp[5] = __uint_as_float(w.z & 0xffff0000u) * 0.125f;
            qp[6] = __uint_as_float(w.w << 16)         * 0.125f;
            qp[7] = __uint_as_float(w.w & 0xffff0000u) * 0.125f;
        }
    }

    float4 o[4];
    float m_r[4], l_r[4];
    #pragma unroll
    for (int j = 0; j < 4; ++j) {
        o[j] = make_float4(0.f, 0.f, 0.f, 0.f);
        m_r[j] = -1e30f; l_r[j] = 0.f;
    }

    for (int kt = 0; kt < SEQ / 64; ++kt) {
        const int k0 = kt * 64;
        if (kt) __syncthreads();
        {
            const size_t rowoff = ((size_t)(b * SEQ + k0 + sr)) * D_MODEL + h * DK + sd0;
            const ushort4* ks = reinterpret_cast<const ushort4*>(Kg + rowoff);
            const ushort4* vs = reinterpret_cast<const ushort4*>(Vg + rowoff);
            #pragma unroll
            for (int u = 0; u < 4; ++u) {
                *reinterpret_cast<ushort4*>(&KsH[sr * 68 + sd0 + 4 * u]) = ks[u];
                *reinterpret_cast<ushort4*>(&VsH[sr * 68 + sd0 + 4 * u]) = vs[u];
            }
        }
        __syncthreads();

        float s[4][4];
        #pragma unroll
        for (int j = 0; j < 4; ++j)
            #pragma unroll
            for (int i = 0; i < 4; ++i) s[j][i] = 0.f;

        for (int d0 = 0; d0 < 64; d0 += 4) {
            float4 q4[4], k4[4];
            #pragma unroll
            for (int j = 0; j < 4; ++j)
                q4[j] = *reinterpret_cast<const float4*>(&Qs[(4 * tq + j) * 68 + d0]);
            #pragma unroll
            for (int i = 0; i < 4; ++i) {
                ushort4 kr = *reinterpret_cast<const ushort4*>(&KsH[(tk + 16 * i) * 68 + d0]);
                k4[i].x = bf2f(kr.x); k4[i].y = bf2f(kr.y);
                k4[i].z = bf2f(kr.z); k4[i].w = bf2f(kr.w);
            }
            #pragma unroll
            for (int j = 0; j < 4; ++j)
                #pragma unroll
                for (int i = 0; i < 4; ++i)
                    s[j][i] += q4[j].x * k4[i].x + q4[j].y * k4[i].y
                             + q4[j].z * k4[i].z + q4[j].w * k4[i].w;
        }

        int mk[4];
        #pragma unroll
        for (int i = 0; i < 4; ++i) mk[i] = mask[b * SEQ + k0 + tk + 16 * i];
        #pragma unroll
        for (int j = 0; j < 4; ++j)
            #pragma unroll
            for (int i = 0; i < 4; ++i)
                if (mk[i] == 0) s[j][i] = -1e9f;

        #pragma unroll
        for (int j = 0; j < 4; ++j) {
            float mx = fmaxf(fmaxf(s[j][0], s[j][1]), fmaxf(s[j][2], s[j][3]));
            #pragma unroll
            for (int off = 1; off < 16; off <<= 1) mx = fmaxf(mx, __shfl_xor(mx, off));
            const float mn = fmaxf(m_r[j], mx);
            const float alpha = __expf(m_r[j] - mn);
            float p[4], psum = 0.f;
            #pragma unroll
            for (int i = 0; i < 4; ++i) { p[i] = __expf(s[j][i] - mn); psum += p[i]; }
            #pragma unroll
            for (int off = 1; off < 16; off <<= 1) psum += __shfl_xor(psum, off);
            l_r[j] = l_r[j] * alpha + psum;
            m_r[j] = mn;
            o[j].x *= alpha; o[j].y *= alpha; o[j].z *= alpha; o[j].w *= alpha;
            #pragma unroll
            for (int i = 0; i < 4; ++i)
                Ps[(4 * tq + j) * 68 + tk + 16 * i] = p[i];
        }
        __syncthreads();

        for (int kk0 = 0; kk0 < 64; kk0 += 4) {
            float4 v4[4];
            #pragma unroll
            for (int u = 0; u < 4; ++u) {
                ushort4 vr = *reinterpret_cast<const ushort4*>(&VsH[(kk0 + u) * 68 + 4 * tk]);
                v4[u].x = bf2f(vr.x); v4[u].y = bf2f(vr.y);
                v4[u].z = bf2f(vr.z); v4[u].w = bf2f(vr.w);
            }
            #pragma unroll
            for (int j = 0; j < 4; ++j) {
                float4 p4 = *reinterpret_cast<const float4*>(&Ps[(4 * tq + j) * 68 + kk0]);
                o[j].x += p4.x * v4[0].x + p4.y * v4[1].x + p4.z * v4[2].x + p4.w * v4[3].x;
                o[j].y += p4.x * v4[0].y + p4.y * v4[1].y + p4.z * v4[2].y + p4.w * v4[3].y;
                o[j].z += p4.x * v4[0].z + p4.y * v4[1].z + p4.z * v4[2].z + p4.w * v4[3].z;
                o[j].w += p4.x * v4[0].w + p4.y * v4[1].w + p4.z * v4[2].w + p4.w * v4[3].w;
            }
        }
    }

    #pragma unroll
    for (int j = 0; j < 4; ++j) {
        const float inv = 1.f / l_r[j];
        bf16* dst = ctx + ((size_t)(b * SEQ + q0 + 4 * tq + j)) * D_MODEL + h * DK + 4 * tk;
        ushort4 pk;
        pk.x = f2bu(o[j].x * inv);
        pk.y = f2bu(o[j].y * inv);
        pk.z = f2bu(o[j].z * inv);
        pk.w = f2bu(o[j].w * inv);
        *reinterpret_cast<ushort4*>(dst) = pk;
    }
}

// y = alpha*(v-mean)/(std+eps)+bias, v = base + add (add always ws bf16), ddof=1.
template<bool BASE_WS, bool OUT_WS>
__global__ __launch_bounds__(256) void ln_kernel(const void* __restrict__ base,
    const bf16* __restrict__ addv, const void* __restrict__ alpha,
    const void* __restrict__ bias, void* __restrict__ outp, const int* __restrict__ flagp)
{
    const bool inF32 = (*flagp) != 0;
    __shared__ float vals[D_MODEL];
    __shared__ float red[256];
    const int row = blockIdx.x, tid = threadIdx.x;

    float lsum = 0.f;
    for (int i = tid; i < D_MODEL; i += 256) {
        const size_t off = (size_t)row * D_MODEL + i;
        float v = (BASE_WS ? toF(((const bf16*)base)[off]) : ld1(base, off, inF32)) + toF(addv[off]);
        vals[i] = v; lsum += v;
    }
    red[tid] = lsum; __syncthreads();
    for (int s = 128; s > 0; s >>= 1) { if (tid < s) red[tid] += red[tid + s]; __syncthreads(); }
    const float mean = red[0] / (float)D_MODEL; __syncthreads();

    float lsq = 0.f;
    for (int i = tid; i < D_MODEL; i += 256) { float dd = vals[i] - mean; lsq += dd * dd; }
    red[tid] = lsq; __syncthreads();
    for (int s = 128; s > 0; s >>= 1) { if (tid < s) red[tid] += red[tid + s]; __syncthreads(); }
    const float var = red[0] / (float)(D_MODEL - 1);
    const float inv = 1.f / (sqrtf(var) + LN_EPS);

    for (int i = tid; i < D_MODEL; i += 256) {
        const size_t off = (size_t)row * D_MODEL + i;
        const float y = ld1(alpha, i, inF32) * (vals[i] - mean) * inv + ld1(bias, i, inF32);
        if (OUT_WS || !inF32) ((bf16*)outp)[off] = __float2bfloat16(y);
        else                  ((float*)outp)[off] = y;
    }
}

extern "C" void kernel_launch(void* const* d_in, const int* in_sizes, int n_in,
                              void* d_out, int out_size, void* d_ws, size_t ws_size,
                              hipStream_t stream)
{
    const void* x    = d_in[0];
    const int*  mask = (const int*)d_in[1];
    const void* wq   = d_in[2];
    const void* wk   = d_in[3];
    const void* wv   = d_in[4];
    const void* wo   = d_in[5];
    const void* wo_b = d_in[6];
    const void* w1   = d_in[7];
    const void* b1   = d_in[8];
    const void* w2   = d_in[9];
    const void* b2   = d_in[10];
    const void* al1  = d_in[11];
    const void* bi1  = d_in[12];
    const void* al2  = d_in[13];
    const void* bi2  = d_in[14];

    // ws plan (56 MB + flag), lifetimes strictly sequential on stream:
    //  [0,8)Qb [8,16)Kb [16,24)Vb [24,32)CTXb            (QKV gemm -> fattn)
    //  [32,38) WQKVT (dead after QKV gemm) -> [32,40) X1b (ln1 output)
    //  [0,2)   WOT over dead Qb (after fattn)
    //  [40,48) ATTb -> W1T (after ln1) -> X2b (after FF1)
    //  [48,56) W2T
    //  [0,32)  FFb over dead Q/K/V/CTX (FF1 output)
    const size_t MB = 1024 * 1024;
    if (ws_size < 56 * MB + 4096) return;   // loud fail: out stays 0 -> absmax 5.1875

    char* ws = (char*)d_ws;
    bf16* Qb    = (bf16*)(ws + 0 * MB);
    bf16* Kb    = (bf16*)(ws + 8 * MB);
    bf16* Vb    = (bf16*)(ws + 16 * MB);
    bf16* CTXb  = (bf16*)(ws + 24 * MB);
    bf16* X1b   = (bf16*)(ws + 32 * MB);
    bf16* WQKVT = (bf16*)(ws + 32 * MB);
    bf16* WOT   = (bf16*)(ws + 0 * MB);
    bf16* ATTb  = (bf16*)(ws + 40 * MB);
    bf16* W1T   = (bf16*)(ws + 40 * MB);
    bf16* X2b   = (bf16*)(ws + 40 * MB);
    bf16* W2T   = (bf16*)(ws + 48 * MB);
    bf16* FFb   = (bf16*)(ws + 0 * MB);
    int*  flagp = (int*)(ws + 56 * MB);

    probe_kernel<<<1, 256, 0, stream>>>(x, flagp);

    dim3 tb(32, 8);
    // Transpose wq,wk,wv -> WQKVT (contiguous, 1M elems each)
    transpose_kernel<<<dim3(32, 32), tb, 0, stream>>>(wq, WQKVT,                D_MODEL, D_MODEL, flagp);
    transpose_kernel<<<dim3(32, 32), tb, 0, stream>>>(wk, WQKVT + 1048576,      D_MODEL, D_MODEL, flagp);
    transpose_kernel<<<dim3(32, 32), tb, 0, stream>>>(wv, WQKVT + 2097152,      D_MODEL, D_MODEL, flagp);

    // Fused QKV: grid.x = 3 * (1024/128) = 24
    mgemm_kernel<true, false, false, 3><<<dim3(24, 32), 256, 0, stream>>>(
        x, WQKVT, nullptr, Qb, ROWS, D_MODEL, D_MODEL, flagp);

    fattn_kernel<<<dim3(BATCH * N_HEADS * (SEQ / 64)), 256, 0, stream>>>(Qb, Kb, Vb, mask, CTXb);

    transpose_kernel<<<dim3(32, 32), tb, 0, stream>>>(wo, WOT, D_MODEL, D_MODEL, flagp);
    mgemm_kernel<false, false, true, 1><<<dim3(8, 32), 256, 0, stream>>>(
        CTXb, WOT, wo_b, ATTb, ROWS, D_MODEL, D_MODEL, flagp);

    ln_kernel<false, true><<<ROWS, 256, 0, stream>>>(x, ATTb, al1, bi1, X1b, flagp);

    transpose_kernel<<<dim3(128, 32), tb, 0, stream>>>(w1, W1T, D_MODEL, D_FF, flagp);
    mgemm_kernel<false, true, true, 1><<<dim3(32, 32), 256, 0, stream>>>(
        X1b, W1T, b1, FFb, ROWS, D_FF, D_MODEL, flagp);

    transpose_kernel<<<dim3(32, 128), tb, 0, stream>>>(w2, W2T, D_FF, D_MODEL, flagp);
    mgemm_kernel<false, false, true, 1><<<dim3(8, 32), 256, 0, stream>>>(
        FFb, W2T, b2, X2b, ROWS, D_MODEL, D_FF, flagp);

    ln_kernel<true, false><<<ROWS, 256, 0, stream>>>(X1b, X2b, al2, bi2, d_out, flagp);
}

// Round 6
// 486.891 us; speedup vs baseline: 12.2836x; 1.9337x over previous
//
#include <hip/hip_runtime.h>
#include <hip/hip_bf16.h>

#define D_MODEL 1024
#define N_HEADS 16
#define DK      64
#define SEQ     2048
#define BATCH   2
#define D_FF    4096
#define ROWS    (BATCH*SEQ)   // 4096
#define LN_EPS  1e-6f
#define SSTR    72            // GEMM LDS row stride (bf16): 64 data + 8 pad
#define KTILE   128           // fattn K-tile
#define PSTR    136           // fattn LDS stride for 128-col tiles (+8 pad)

typedef __hip_bfloat16 bf16;
typedef __attribute__((ext_vector_type(8))) short frag8;   // 8 bf16 (MFMA A/B)
typedef __attribute__((ext_vector_type(4))) float facc4;   // 4 f32 (MFMA C/D)

__device__ inline float bf2f(unsigned short u){ return __uint_as_float(((unsigned)u) << 16); }
__device__ inline float toF(bf16 v){ return __bfloat162float(v); }
__device__ inline unsigned short f2bu(float f){ bf16 h = __float2bfloat16(f); return *reinterpret_cast<unsigned short*>(&h); }

__device__ inline float ld1(const void* p, size_t idx, bool f32) {
    return f32 ? ((const float*)p)[idx] : toF(((const bf16*)p)[idx]);
}

struct U8 { unsigned short v[8]; };
__device__ inline U8 ld8bf(const void* p, size_t idx, bool f32) {
    U8 r;
    if (!f32) {
        *reinterpret_cast<uint4*>(r.v) = *reinterpret_cast<const uint4*>((const unsigned short*)p + idx);
    } else {
        const float* f = (const float*)p + idx;
        const float4 a = *reinterpret_cast<const float4*>(f);
        const float4 b = *reinterpret_cast<const float4*>(f + 4);
        r.v[0]=f2bu(a.x); r.v[1]=f2bu(a.y); r.v[2]=f2bu(a.z); r.v[3]=f2bu(a.w);
        r.v[4]=f2bu(b.x); r.v[5]=f2bu(b.y); r.v[6]=f2bu(b.z); r.v[7]=f2bu(b.w);
    }
    return r;
}

// Dtype probe: fp32 bits misread as bf16 give Inf/NaN/huge values.
__global__ void probe_kernel(const void* __restrict__ xp, int* __restrict__ flag) {
    __shared__ int hit;
    if (threadIdx.x == 0) hit = 0;
    __syncthreads();
    const bf16* p = (const bf16*)xp;
    int bad = 0;
    for (int i = threadIdx.x; i < 8192; i += 256) {
        float v = fabsf(toF(p[i]));
        if (!(v <= 1e5f)) bad = 1;
    }
    if (bad) atomicOr(&hit, 1);
    __syncthreads();
    if (threadIdx.x == 0) *flag = hit;   // 1 => inputs are fp32
}

// WT[n][k] = W[k][n], output bf16. grid (N/32, K/32), block (32,8).
__global__ __launch_bounds__(256) void transpose_kernel(const void* __restrict__ W,
    bf16* __restrict__ WT, int K, int N, const int* __restrict__ flagp)
{
    const bool f32 = (*flagp) != 0;
    __shared__ float tile[32][33];
    const int tx = threadIdx.x, ty = threadIdx.y;
    const int n0 = blockIdx.x * 32, k0 = blockIdx.y * 32;
    #pragma unroll
    for (int r = 0; r < 4; ++r)
        tile[ty + 8*r][tx] = ld1(W, (size_t)(k0 + ty + 8*r) * N + n0 + tx, f32);
    __syncthreads();
    #pragma unroll
    for (int r = 0; r < 4; ++r)
        WT[(size_t)(n0 + ty + 8*r) * K + k0 + tx] = __float2bfloat16(tile[tx][ty + 8*r]);
}

// VT[(b*16+h)*64 + d][s] = V[(b*SEQ+s)*D_MODEL + h*64 + d]. grid (SEQ/32, 2, 32).
__global__ __launch_bounds__(256) void vtrans_kernel(const bf16* __restrict__ V,
    bf16* __restrict__ VT)
{
    __shared__ unsigned short tile[32][33];
    const int tx = threadIdx.x, ty = threadIdx.y;
    const int s0 = blockIdx.x * 32, d0 = blockIdx.y * 32;
    const int bh = blockIdx.z, b = bh >> 4, h = bh & 15;
    #pragma unroll
    for (int r = 0; r < 4; ++r)
        tile[ty + 8*r][tx] = *reinterpret_cast<const unsigned short*>(
            V + ((size_t)(b * SEQ + s0 + ty + 8*r)) * D_MODEL + h * DK + d0 + tx);
    __syncthreads();
    #pragma unroll
    for (int r = 0; r < 4; ++r)
        *reinterpret_cast<unsigned short*>(
            VT + ((size_t)(bh * DK + d0 + ty + 8*r)) * SEQ + s0 + tx) = tile[tx][ty + 8*r];
}

// MFMA GEMM: C[M,N] bf16 = A[M,K] @ BT[N,K]^T (+bias)(+relu), fp32 accum.
// 128x128 tile, 4 waves, BK=64. NMAT>1: fused QKV (N must be 1024).
template<bool A_F, bool RELU, bool BIAS, int NMAT>
__global__ __launch_bounds__(256) void mgemm_kernel(const void* __restrict__ A,
    const bf16* __restrict__ BT, const void* __restrict__ bias,
    bf16* __restrict__ C, int M, int N, int K, const int* __restrict__ flagp)
{
    const bool inF32 = (*flagp) != 0;
    const bool aF32  = A_F ? inF32 : false;

    __shared__ unsigned short sA[128 * SSTR];
    __shared__ unsigned short sB[128 * SSTR];

    int which = 0, colb = blockIdx.x;
    if (NMAT > 1) { which = blockIdx.x >> 3; colb = blockIdx.x & 7; }
    const bf16* Bp = BT + (size_t)which * N * K;
    bf16*       Cp = C  + (size_t)which * M * N;

    const int row0 = blockIdx.y * 128;
    const int col0 = colb * 128;

    const int t    = threadIdx.x;
    const int wave = t >> 6;
    const int lane = t & 63;
    const int lm   = lane & 15;
    const int q    = lane >> 4;
    const int wm   = (wave & 1) * 64;
    const int wn   = (wave >> 1) * 64;

    facc4 acc[4][4];
    #pragma unroll
    for (int i = 0; i < 4; ++i)
        #pragma unroll
        for (int j = 0; j < 4; ++j)
            acc[i][j] = (facc4){0.f, 0.f, 0.f, 0.f};

    for (int k0 = 0; k0 < K; k0 += 64) {
        if (k0) __syncthreads();
        #pragma unroll
        for (int u = 0; u < 4; ++u) {
            const int ci = u * 256 + t;
            const int r = ci >> 3, c = ci & 7;
            U8 d = ld8bf(A, (size_t)(row0 + r) * K + k0 + 8 * c, aF32);
            *reinterpret_cast<uint4*>(&sA[r * SSTR + 8 * c]) = *reinterpret_cast<const uint4*>(d.v);
            U8 e = ld8bf(Bp, (size_t)(col0 + r) * K + k0 + 8 * c, false);
            *reinterpret_cast<uint4*>(&sB[r * SSTR + 8 * c]) = *reinterpret_cast<const uint4*>(e.v);
        }
        __syncthreads();

        #pragma unroll
        for (int kk = 0; kk < 64; kk += 32) {
            frag8 af[4], bfr[4];
            #pragma unroll
            for (int im = 0; im < 4; ++im)
                af[im] = *reinterpret_cast<const frag8*>(&sA[(wm + 16*im + lm) * SSTR + kk + 8*q]);
            #pragma unroll
            for (int in = 0; in < 4; ++in)
                bfr[in] = *reinterpret_cast<const frag8*>(&sB[(wn + 16*in + lm) * SSTR + kk + 8*q]);
            #pragma unroll
            for (int im = 0; im < 4; ++im)
                #pragma unroll
                for (int in = 0; in < 4; ++in)
                    acc[im][in] = __builtin_amdgcn_mfma_f32_16x16x32_bf16(af[im], bfr[in], acc[im][in], 0, 0, 0);
        }
    }

    #pragma unroll
    for (int in = 0; in < 4; ++in) {
        const int col = col0 + wn + 16*in + lm;
        float bv = 0.f;
        if (BIAS) bv = ld1(bias, col, inF32);
        #pragma unroll
        for (int im = 0; im < 4; ++im) {
            #pragma unroll
            for (int r = 0; r < 4; ++r) {
                const int row = row0 + wm + 16*im + 4*q + r;
                float v = acc[im][in][r] + bv;
                if (RELU) v = fmaxf(v, 0.f);
                Cp[(size_t)row * N + col] = __float2bfloat16(v);
            }
        }
    }
}

// MFMA flash attention. Block = (qt, h, b): 64 q-rows, 4 waves x 16 q-rows each.
// K-tile = 128. Q/K from [s][d] layout; V from pre-transposed VT [b,h][d][s].
__global__ __launch_bounds__(256) void fattn_kernel(
    const bf16* __restrict__ Qg, const bf16* __restrict__ Kg,
    const bf16* __restrict__ VTg, const int* __restrict__ mask,
    bf16* __restrict__ ctx)
{
    __shared__ unsigned short Qs[64 * SSTR];          //  9.2 KB (scaled bf16)
    __shared__ unsigned short Ks[KTILE * SSTR];       // 18.4 KB
    __shared__ unsigned short VTs[DK * PSTR];         // 17.4 KB
    __shared__ unsigned short Ps[4 * 16 * PSTR];      // 17.4 KB (per-wave P)
    __shared__ float madd[KTILE];

    const int t    = threadIdx.x;
    const int qt   = blockIdx.x;
    const int h    = blockIdx.y;
    const int b    = blockIdx.z;
    const int q0   = qt * 64;
    const int wave = t >> 6;
    const int lane = t & 63;
    const int lm   = lane & 15;
    const int qd   = lane >> 4;

    // ---- stage Q once, pre-scaled by 0.125 (exact in bf16) ----
    {
        const int sr = t >> 2, sd0 = (t & 3) * 16;
        const unsigned short* src = (const unsigned short*)
            (Qg + ((size_t)(b * SEQ + q0 + sr)) * D_MODEL + h * DK + sd0);
        unsigned short qi[16], qo[16];
        *reinterpret_cast<uint4*>(&qi[0]) = *reinterpret_cast<const uint4*>(src);
        *reinterpret_cast<uint4*>(&qi[8]) = *reinterpret_cast<const uint4*>(src + 8);
        #pragma unroll
        for (int u = 0; u < 16; ++u) qo[u] = f2bu(bf2f(qi[u]) * 0.125f);
        *reinterpret_cast<uint4*>(&Qs[sr * SSTR + sd0])     = *reinterpret_cast<const uint4*>(&qo[0]);
        *reinterpret_cast<uint4*>(&Qs[sr * SSTR + sd0 + 8]) = *reinterpret_cast<const uint4*>(&qo[8]);
    }

    facc4 accO[4];
    float m_r[4], l_r[4];
    #pragma unroll
    for (int r = 0; r < 4; ++r) { m_r[r] = -1e30f; l_r[r] = 0.f; }
    #pragma unroll
    for (int in = 0; in < 4; ++in) accO[in] = (facc4){0.f, 0.f, 0.f, 0.f};

    for (int kt = 0; kt < SEQ / KTILE; ++kt) {
        const int k0 = kt * KTILE;
        __syncthreads();   // protect Ks/VTs (and Qs on first iter)

        // ---- stage K tile [128 kk][64 d] ----
        #pragma unroll
        for (int u = 0; u < 4; ++u) {
            const int ci = u * 256 + t;
            const int r = ci >> 3, c = ci & 7;
            *reinterpret_cast<uint4*>(&Ks[r * SSTR + 8 * c]) =
                *reinterpret_cast<const uint4*>(Kg + ((size_t)(b * SEQ + k0 + r)) * D_MODEL + h * DK + 8 * c);
        }
        // ---- stage VT tile [64 d][128 kk] ----
        #pragma unroll
        for (int u = 0; u < 4; ++u) {
            const int ci = u * 256 + t;
            const int r = ci >> 4, c = ci & 15;
            *reinterpret_cast<uint4*>(&VTs[r * PSTR + 8 * c]) =
                *reinterpret_cast<const uint4*>(VTg + ((size_t)((b * N_HEADS + h) * DK + r)) * SEQ + k0 + 8 * c);
        }
        if (t < KTILE) madd[t] = (mask[b * SEQ + k0 + t] == 0) ? -1e9f : 0.f;
        __syncthreads();

        // ---- S[16q][128kk] = Qs @ Ks^T via MFMA ----
        facc4 accS[8];
        #pragma unroll
        for (int i = 0; i < 8; ++i) accS[i] = (facc4){0.f, 0.f, 0.f, 0.f};
        frag8 qf[2];
        #pragma unroll
        for (int s2 = 0; s2 < 2; ++s2)
            qf[s2] = *reinterpret_cast<const frag8*>(&Qs[(16 * wave + lm) * SSTR + 32 * s2 + 8 * qd]);
        #pragma unroll
        for (int i = 0; i < 8; ++i) {
            #pragma unroll
            for (int s2 = 0; s2 < 2; ++s2) {
                frag8 kf = *reinterpret_cast<const frag8*>(&Ks[(16 * i + lm) * SSTR + 32 * s2 + 8 * qd]);
                accS[i] = __builtin_amdgcn_mfma_f32_16x16x32_bf16(qf[s2], kf, accS[i], 0, 0, 0);
            }
        }

        // ---- online softmax (rows = qd*4+r, cols = 16i+lm) ----
        float madv[8];
        #pragma unroll
        for (int i = 0; i < 8; ++i) madv[i] = madd[16 * i + lm];

        float mx[4];
        #pragma unroll
        for (int r = 0; r < 4; ++r) {
            float m0 = -1e30f;
            #pragma unroll
            for (int i = 0; i < 8; ++i) m0 = fmaxf(m0, accS[i][r] + madv[i]);
            #pragma unroll
            for (int off = 1; off < 16; off <<= 1) m0 = fmaxf(m0, __shfl_xor(m0, off));
            mx[r] = m0;
        }

        float alpha[4], mn[4], psum[4];
        #pragma unroll
        for (int r = 0; r < 4; ++r) {
            mn[r] = fmaxf(m_r[r], mx[r]);
            alpha[r] = __expf(m_r[r] - mn[r]);
            m_r[r] = mn[r];
            psum[r] = 0.f;
        }
        unsigned short* Pw = &Ps[wave * 16 * PSTR];
        #pragma unroll
        for (int i = 0; i < 8; ++i) {
            #pragma unroll
            for (int r = 0; r < 4; ++r) {
                float p = __expf(accS[i][r] + madv[i] - mn[r]);
                psum[r] += p;
                Pw[(qd * 4 + r) * PSTR + 16 * i + lm] = f2bu(p);
            }
        }
        #pragma unroll
        for (int r = 0; r < 4; ++r) {
            float s = psum[r];
            #pragma unroll
            for (int off = 1; off < 16; off <<= 1) s += __shfl_xor(s, off);
            l_r[r] = l_r[r] * alpha[r] + s;
            #pragma unroll
            for (int in = 0; in < 4; ++in) accO[in][r] *= alpha[r];
        }

        // ---- O += P @ V  (A-frag from Ps, B-frag from VTs) ----
        #pragma unroll
        for (int c = 0; c < 4; ++c) {
            frag8 pf = *reinterpret_cast<const frag8*>(&Pw[lm * PSTR + 32 * c + 8 * qd]);
            #pragma unroll
            for (int in = 0; in < 4; ++in) {
                frag8 vf = *reinterpret_cast<const frag8*>(&VTs[(16 * in + lm) * PSTR + 32 * c + 8 * qd]);
                accO[in] = __builtin_amdgcn_mfma_f32_16x16x32_bf16(pf, vf, accO[in], 0, 0, 0);
            }
        }
    }

    // ---- normalize + store (C layout: col=lm, row=qd*4+r) ----
    float inv[4];
    #pragma unroll
    for (int r = 0; r < 4; ++r) inv[r] = 1.f / l_r[r];
    #pragma unroll
    for (int in = 0; in < 4; ++in)
        #pragma unroll
        for (int r = 0; r < 4; ++r)
            ctx[((size_t)(b * SEQ + q0 + 16 * wave + qd * 4 + r)) * D_MODEL + h * DK + 16 * in + lm]
                = __float2bfloat16(accO[in][r] * inv[r]);
}

// y = alpha*(v-mean)/(std+eps)+bias, v = base + add (add always ws bf16), ddof=1.
template<bool BASE_WS, bool OUT_WS>
__global__ __launch_bounds__(256) void ln_kernel(const void* __restrict__ base,
    const bf16* __restrict__ addv, const void* __restrict__ alpha,
    const void* __restrict__ bias, void* __restrict__ outp, const int* __restrict__ flagp)
{
    const bool inF32 = (*flagp) != 0;
    __shared__ float vals[D_MODEL];
    __shared__ float red[256];
    const int row = blockIdx.x, tid = threadIdx.x;

    float lsum = 0.f;
    for (int i = tid; i < D_MODEL; i += 256) {
        const size_t off = (size_t)row * D_MODEL + i;
        float v = (BASE_WS ? toF(((const bf16*)base)[off]) : ld1(base, off, inF32)) + toF(addv[off]);
        vals[i] = v; lsum += v;
    }
    red[tid] = lsum; __syncthreads();
    for (int s = 128; s > 0; s >>= 1) { if (tid < s) red[tid] += red[tid + s]; __syncthreads(); }
    const float mean = red[0] / (float)D_MODEL; __syncthreads();

    float lsq = 0.f;
    for (int i = tid; i < D_MODEL; i += 256) { float dd = vals[i] - mean; lsq += dd * dd; }
    red[tid] = lsq; __syncthreads();
    for (int s = 128; s > 0; s >>= 1) { if (tid < s) red[tid] += red[tid + s]; __syncthreads(); }
    const float var = red[0] / (float)(D_MODEL - 1);
    const float inv = 1.f / (sqrtf(var) + LN_EPS);

    for (int i = tid; i < D_MODEL; i += 256) {
        const size_t off = (size_t)row * D_MODEL + i;
        const float y = ld1(alpha, i, inF32) * (vals[i] - mean) * inv + ld1(bias, i, inF32);
        if (OUT_WS || !inF32) ((bf16*)outp)[off] = __float2bfloat16(y);
        else                  ((float*)outp)[off] = y;
    }
}

extern "C" void kernel_launch(void* const* d_in, const int* in_sizes, int n_in,
                              void* d_out, int out_size, void* d_ws, size_t ws_size,
                              hipStream_t stream)
{
    const void* x    = d_in[0];
    const int*  mask = (const int*)d_in[1];
    const void* wq   = d_in[2];
    const void* wk   = d_in[3];
    const void* wv   = d_in[4];
    const void* wo   = d_in[5];
    const void* wo_b = d_in[6];
    const void* w1   = d_in[7];
    const void* b1   = d_in[8];
    const void* w2   = d_in[9];
    const void* b2   = d_in[10];
    const void* al1  = d_in[11];
    const void* bi1  = d_in[12];
    const void* al2  = d_in[13];
    const void* bi2  = d_in[14];

    // ws plan (56 MB + flag), strictly sequential lifetimes:
    //  [0,8)Qb [8,16)Kb [16,24)Vb [24,32)VTb
    //  [32,38)WQKVT -> [32,40)CTXb (fattn out) -> [32,40)X1b (ln1 out, CTX dead)
    //  [0,2)WOT over dead Qb
    //  [40,48)ATTb -> W1T -> X2b
    //  [48,56)W2T ; [0,32)FFb over dead Q/K/V/VT
    const size_t MB = 1024 * 1024;
    if (ws_size < 56 * MB + 4096) return;   // loud fail: out stays 0

    char* ws = (char*)d_ws;
    bf16* Qb    = (bf16*)(ws + 0 * MB);
    bf16* Kb    = (bf16*)(ws + 8 * MB);
    bf16* Vb    = (bf16*)(ws + 16 * MB);
    bf16* VTb   = (bf16*)(ws + 24 * MB);
    bf16* WQKVT = (bf16*)(ws + 32 * MB);
    bf16* CTXb  = (bf16*)(ws + 32 * MB);
    bf16* X1b   = (bf16*)(ws + 32 * MB);
    bf16* WOT   = (bf16*)(ws + 0 * MB);
    bf16* ATTb  = (bf16*)(ws + 40 * MB);
    bf16* W1T   = (bf16*)(ws + 40 * MB);
    bf16* X2b   = (bf16*)(ws + 40 * MB);
    bf16* W2T   = (bf16*)(ws + 48 * MB);
    bf16* FFb   = (bf16*)(ws + 0 * MB);
    int*  flagp = (int*)(ws + 56 * MB);

    probe_kernel<<<1, 256, 0, stream>>>(x, flagp);

    dim3 tb(32, 8);
    transpose_kernel<<<dim3(32, 32), tb, 0, stream>>>(wq, WQKVT,           D_MODEL, D_MODEL, flagp);
    transpose_kernel<<<dim3(32, 32), tb, 0, stream>>>(wk, WQKVT + 1048576, D_MODEL, D_MODEL, flagp);
    transpose_kernel<<<dim3(32, 32), tb, 0, stream>>>(wv, WQKVT + 2097152, D_MODEL, D_MODEL, flagp);

    mgemm_kernel<true, false, false, 3><<<dim3(24, 32), 256, 0, stream>>>(
        x, WQKVT, nullptr, Qb, ROWS, D_MODEL, D_MODEL, flagp);

    vtrans_kernel<<<dim3(SEQ / 32, 2, BATCH * N_HEADS), tb, 0, stream>>>(Vb, VTb);

    fattn_kernel<<<dim3(SEQ / 64, N_HEADS, BATCH), 256, 0, stream>>>(Qb, Kb, VTb, mask, CTXb);

    transpose_kernel<<<dim3(32, 32), tb, 0, stream>>>(wo, WOT, D_MODEL, D_MODEL, flagp);
    mgemm_kernel<false, false, true, 1><<<dim3(8, 32), 256, 0, stream>>>(
        CTXb, WOT, wo_b, ATTb, ROWS, D_MODEL, D_MODEL, flagp);

    ln_kernel<false, true><<<ROWS, 256, 0, stream>>>(x, ATTb, al1, bi1, X1b, flagp);

    transpose_kernel<<<dim3(128, 32), tb, 0, stream>>>(w1, W1T, D_MODEL, D_FF, flagp);
    mgemm_kernel<false, true, true, 1><<<dim3(32, 32), 256, 0, stream>>>(
        X1b, W1T, b1, FFb, ROWS, D_FF, D_MODEL, flagp);

    transpose_kernel<<<dim3(32, 128), tb, 0, stream>>>(w2, W2T, D_FF, D_MODEL, flagp);
    mgemm_kernel<false, false, true, 1><<<dim3(8, 32), 256, 0, stream>>>(
        FFb, W2T, b2, X2b, ROWS, D_MODEL, D_FF, flagp);

    ln_kernel<true, false><<<ROWS, 256, 0, stream>>>(X1b, X2b, al2, bi2, d_out, flagp);
}

// Round 7
// 460.475 us; speedup vs baseline: 12.9883x; 1.0574x over previous
//
#include <hip/hip_runtime.h>
#include <hip/hip_bf16.h>

#define D_MODEL 1024
#define N_HEADS 16
#define DK      64
#define SEQ     2048
#define BATCH   2
#define D_FF    4096
#define ROWS    (BATCH*SEQ)   // 4096
#define LN_EPS  1e-6f
#define SSTR    72            // fattn LDS row stride (bf16): 64 data + 8 pad
#define KTILE   128           // fattn K-tile
#define PSTR    136           // fattn LDS stride for 128-col tiles (+8 pad)

typedef __hip_bfloat16 bf16;
typedef __attribute__((ext_vector_type(8))) short frag8;   // 8 bf16 (MFMA A/B)
typedef __attribute__((ext_vector_type(4))) float facc4;   // 4 f32 (MFMA C/D)

__device__ inline float bf2f(unsigned short u){ return __uint_as_float(((unsigned)u) << 16); }
__device__ inline float toF(bf16 v){ return __bfloat162float(v); }
__device__ inline unsigned short f2bu(float f){ bf16 h = __float2bfloat16(f); return *reinterpret_cast<unsigned short*>(&h); }

__device__ inline float ld1(const void* p, size_t idx, bool f32) {
    return f32 ? ((const float*)p)[idx] : toF(((const bf16*)p)[idx]);
}

struct U8 { unsigned short v[8]; };
__device__ inline U8 ld8bf(const void* p, size_t idx, bool f32) {
    U8 r;
    if (!f32) {
        *reinterpret_cast<uint4*>(r.v) = *reinterpret_cast<const uint4*>((const unsigned short*)p + idx);
    } else {
        const float* f = (const float*)p + idx;
        const float4 a = *reinterpret_cast<const float4*>(f);
        const float4 b = *reinterpret_cast<const float4*>(f + 4);
        r.v[0]=f2bu(a.x); r.v[1]=f2bu(a.y); r.v[2]=f2bu(a.z); r.v[3]=f2bu(a.w);
        r.v[4]=f2bu(b.x); r.v[5]=f2bu(b.y); r.v[6]=f2bu(b.z); r.v[7]=f2bu(b.w);
    }
    return r;
}

// Async global->LDS, 16B per lane. LDS dst is wave-uniform base; HW writes
// lane i at dst + i*16B. CK-style addrspace casts via uintptr (AS3 = low 32 bits).
__device__ inline void gld16(const void* g, void* l) {
    __builtin_amdgcn_global_load_lds(
        reinterpret_cast<const __attribute__((address_space(1))) void*>(
            reinterpret_cast<uintptr_t>(g)),
        reinterpret_cast<__attribute__((address_space(3))) void*>(
            (unsigned int)reinterpret_cast<uintptr_t>(l)),
        16, 0, 0);
}

// Dtype probe: fp32 bits misread as bf16 give Inf/NaN/huge values.
__global__ void probe_kernel(const void* __restrict__ xp, int* __restrict__ flag) {
    __shared__ int hit;
    if (threadIdx.x == 0) hit = 0;
    __syncthreads();
    const bf16* p = (const bf16*)xp;
    int bad = 0;
    for (int i = threadIdx.x; i < 8192; i += 256) {
        float v = fabsf(toF(p[i]));
        if (!(v <= 1e5f)) bad = 1;
    }
    if (bad) atomicOr(&hit, 1);
    __syncthreads();
    if (threadIdx.x == 0) *flag = hit;   // 1 => inputs are fp32
}

// x (flag dtype) -> canonical bf16 ws buffer. 8 elems/thread.
__global__ __launch_bounds__(256) void xcvt_kernel(const void* __restrict__ x,
    bf16* __restrict__ out, const int* __restrict__ flagp)
{
    const bool f32 = (*flagp) != 0;
    const size_t i = ((size_t)blockIdx.x * 256 + threadIdx.x) * 8;
    U8 d = ld8bf(x, i, f32);
    *reinterpret_cast<uint4*>(out + i) = *reinterpret_cast<const uint4*>(d.v);
}

// WT[n][k] = W[k][n], output bf16. grid (N/32, K/32), block (32,8).
__global__ __launch_bounds__(256) void transpose_kernel(const void* __restrict__ W,
    bf16* __restrict__ WT, int K, int N, const int* __restrict__ flagp)
{
    const bool f32 = (*flagp) != 0;
    __shared__ float tile[32][33];
    const int tx = threadIdx.x, ty = threadIdx.y;
    const int n0 = blockIdx.x * 32, k0 = blockIdx.y * 32;
    #pragma unroll
    for (int r = 0; r < 4; ++r)
        tile[ty + 8*r][tx] = ld1(W, (size_t)(k0 + ty + 8*r) * N + n0 + tx, f32);
    __syncthreads();
    #pragma unroll
    for (int r = 0; r < 4; ++r)
        WT[(size_t)(n0 + ty + 8*r) * K + k0 + tx] = __float2bfloat16(tile[tx][ty + 8*r]);
}

// VT[(b*16+h)*64 + d][s] = V[(b*SEQ+s)*D_MODEL + h*64 + d]. grid (SEQ/32, 2, 32).
__global__ __launch_bounds__(256) void vtrans_kernel(const bf16* __restrict__ V,
    bf16* __restrict__ VT)
{
    __shared__ unsigned short tile[32][33];
    const int tx = threadIdx.x, ty = threadIdx.y;
    const int s0 = blockIdx.x * 32, d0 = blockIdx.y * 32;
    const int bh = blockIdx.z, b = bh >> 4, h = bh & 15;
    #pragma unroll
    for (int r = 0; r < 4; ++r)
        tile[ty + 8*r][tx] = *reinterpret_cast<const unsigned short*>(
            V + ((size_t)(b * SEQ + s0 + ty + 8*r)) * D_MODEL + h * DK + d0 + tx);
    __syncthreads();
    #pragma unroll
    for (int r = 0; r < 4; ++r)
        *reinterpret_cast<unsigned short*>(
            VT + ((size_t)(bh * DK + d0 + ty + 8*r)) * SEQ + s0 + tx) = tile[tx][ty + 8*r];
}

// MFMA GEMM v2: C[M,N] bf16 = A[M,K]bf16 @ BT[N,K]bf16^T (+bias)(+relu).
// 128x128 tile, 4 waves, BK=64. global_load_lds 16B staging into unpadded LDS
// with XOR swizzle: chunk c (16B) of row r stored at position c^(r&7).
// NMAT>1: fused QKV (N must be 1024).
template<bool RELU, bool BIAS, int NMAT>
__global__ __launch_bounds__(256) void mgemm_kernel(const bf16* __restrict__ A,
    const bf16* __restrict__ BT, const void* __restrict__ bias,
    bf16* __restrict__ C, int M, int N, int K, const int* __restrict__ flagp)
{
    const bool inF32 = (*flagp) != 0;

    __shared__ unsigned short sA[128 * 64];   // 16 KB
    __shared__ unsigned short sB[128 * 64];   // 16 KB

    int which = 0, colb = blockIdx.x;
    if (NMAT > 1) { which = blockIdx.x >> 3; colb = blockIdx.x & 7; }
    const bf16* Bp = BT + (size_t)which * N * K;
    bf16*       Cp = C  + (size_t)which * M * N;

    const int row0 = blockIdx.y * 128;
    const int col0 = colb * 128;

    const int t    = threadIdx.x;
    const int wave = t >> 6;
    const int lane = t & 63;
    const int lm   = lane & 15;
    const int q    = lane >> 4;
    const int wm   = (wave & 1) * 64;
    const int wn   = (wave >> 1) * 64;

    facc4 acc[4][4];
    #pragma unroll
    for (int i = 0; i < 4; ++i)
        #pragma unroll
        for (int j = 0; j < 4; ++j)
            acc[i][j] = (facc4){0.f, 0.f, 0.f, 0.f};

    for (int k0 = 0; k0 < K; k0 += 64) {
        __syncthreads();   // previous tile's reads done before overwrite
        // Stage: 1024 chunks of 16B per buffer; 4 insts/wave/buffer.
        #pragma unroll
        for (int j = 0; j < 4; ++j) {
            const int ch = (wave * 4 + j) * 64 + lane;   // 0..1023
            const int r  = ch >> 3;
            const int cs = ch & 7;
            const int c  = cs ^ (r & 7);                 // global chunk fetched
            gld16(A  + (size_t)(row0 + r) * K + k0 + 8 * c, &sA[(wave * 4 + j) * 512]);
            gld16(Bp + (size_t)(col0 + r) * K + k0 + 8 * c, &sB[(wave * 4 + j) * 512]);
        }
        __syncthreads();   // drains vmcnt (global_load_lds complete)

        #pragma unroll
        for (int kk = 0; kk < 64; kk += 32) {
            const int cr = (kk >> 3) + q;                // requested chunk 4*s2+q
            frag8 af[4], bfr[4];
            #pragma unroll
            for (int im = 0; im < 4; ++im) {
                const int m = wm + 16 * im + lm;
                af[im] = *reinterpret_cast<const frag8*>(&sA[m * 64 + ((cr ^ (m & 7)) << 3)]);
            }
            #pragma unroll
            for (int in = 0; in < 4; ++in) {
                const int n = wn + 16 * in + lm;
                bfr[in] = *reinterpret_cast<const frag8*>(&sB[n * 64 + ((cr ^ (n & 7)) << 3)]);
            }
            #pragma unroll
            for (int im = 0; im < 4; ++im)
                #pragma unroll
                for (int in = 0; in < 4; ++in)
                    acc[im][in] = __builtin_amdgcn_mfma_f32_16x16x32_bf16(af[im], bfr[in], acc[im][in], 0, 0, 0);
        }
    }

    // Epilogue: C/D layout col=lane&15, row=quad*4+reg.
    #pragma unroll
    for (int in = 0; in < 4; ++in) {
        const int col = col0 + wn + 16*in + lm;
        float bv = 0.f;
        if (BIAS) bv = ld1(bias, col, inF32);
        #pragma unroll
        for (int im = 0; im < 4; ++im) {
            #pragma unroll
            for (int r = 0; r < 4; ++r) {
                const int row = row0 + wm + 16*im + 4*q + r;
                float v = acc[im][in][r] + bv;
                if (RELU) v = fmaxf(v, 0.f);
                Cp[(size_t)row * N + col] = __float2bfloat16(v);
            }
        }
    }
}

// MFMA flash attention. Block = (qt, h, b): 64 q-rows, 4 waves x 16 q-rows each.
__global__ __launch_bounds__(256) void fattn_kernel(
    const bf16* __restrict__ Qg, const bf16* __restrict__ Kg,
    const bf16* __restrict__ VTg, const int* __restrict__ mask,
    bf16* __restrict__ ctx)
{
    __shared__ unsigned short Qs[64 * SSTR];
    __shared__ unsigned short Ks[KTILE * SSTR];
    __shared__ unsigned short VTs[DK * PSTR];
    __shared__ unsigned short Ps[4 * 16 * PSTR];
    __shared__ float madd[KTILE];

    const int t    = threadIdx.x;
    const int qt   = blockIdx.x;
    const int h    = blockIdx.y;
    const int b    = blockIdx.z;
    const int q0   = qt * 64;
    const int wave = t >> 6;
    const int lane = t & 63;
    const int lm   = lane & 15;
    const int qd   = lane >> 4;

    {
        const int sr = t >> 2, sd0 = (t & 3) * 16;
        const unsigned short* src = (const unsigned short*)
            (Qg + ((size_t)(b * SEQ + q0 + sr)) * D_MODEL + h * DK + sd0);
        unsigned short qi[16], qo[16];
        *reinterpret_cast<uint4*>(&qi[0]) = *reinterpret_cast<const uint4*>(src);
        *reinterpret_cast<uint4*>(&qi[8]) = *reinterpret_cast<const uint4*>(src + 8);
        #pragma unroll
        for (int u = 0; u < 16; ++u) qo[u] = f2bu(bf2f(qi[u]) * 0.125f);
        *reinterpret_cast<uint4*>(&Qs[sr * SSTR + sd0])     = *reinterpret_cast<const uint4*>(&qo[0]);
        *reinterpret_cast<uint4*>(&Qs[sr * SSTR + sd0 + 8]) = *reinterpret_cast<const uint4*>(&qo[8]);
    }

    facc4 accO[4];
    float m_r[4], l_r[4];
    #pragma unroll
    for (int r = 0; r < 4; ++r) { m_r[r] = -1e30f; l_r[r] = 0.f; }
    #pragma unroll
    for (int in = 0; in < 4; ++in) accO[in] = (facc4){0.f, 0.f, 0.f, 0.f};

    for (int kt = 0; kt < SEQ / KTILE; ++kt) {
        const int k0 = kt * KTILE;
        __syncthreads();

        #pragma unroll
        for (int u = 0; u < 4; ++u) {
            const int ci = u * 256 + t;
            const int r = ci >> 3, c = ci & 7;
            *reinterpret_cast<uint4*>(&Ks[r * SSTR + 8 * c]) =
                *reinterpret_cast<const uint4*>(Kg + ((size_t)(b * SEQ + k0 + r)) * D_MODEL + h * DK + 8 * c);
        }
        #pragma unroll
        for (int u = 0; u < 4; ++u) {
            const int ci = u * 256 + t;
            const int r = ci >> 4, c = ci & 15;
            *reinterpret_cast<uint4*>(&VTs[r * PSTR + 8 * c]) =
                *reinterpret_cast<const uint4*>(VTg + ((size_t)((b * N_HEADS + h) * DK + r)) * SEQ + k0 + 8 * c);
        }
        if (t < KTILE) madd[t] = (mask[b * SEQ + k0 + t] == 0) ? -1e9f : 0.f;
        __syncthreads();

        facc4 accS[8];
        #pragma unroll
        for (int i = 0; i < 8; ++i) accS[i] = (facc4){0.f, 0.f, 0.f, 0.f};
        frag8 qf[2];
        #pragma unroll
        for (int s2 = 0; s2 < 2; ++s2)
            qf[s2] = *reinterpret_cast<const frag8*>(&Qs[(16 * wave + lm) * SSTR + 32 * s2 + 8 * qd]);
        #pragma unroll
        for (int i = 0; i < 8; ++i) {
            #pragma unroll
            for (int s2 = 0; s2 < 2; ++s2) {
                frag8 kf = *reinterpret_cast<const frag8*>(&Ks[(16 * i + lm) * SSTR + 32 * s2 + 8 * qd]);
                accS[i] = __builtin_amdgcn_mfma_f32_16x16x32_bf16(qf[s2], kf, accS[i], 0, 0, 0);
            }
        }

        float madv[8];
        #pragma unroll
        for (int i = 0; i < 8; ++i) madv[i] = madd[16 * i + lm];

        float mx[4];
        #pragma unroll
        for (int r = 0; r < 4; ++r) {
            float m0 = -1e30f;
            #pragma unroll
            for (int i = 0; i < 8; ++i) m0 = fmaxf(m0, accS[i][r] + madv[i]);
            #pragma unroll
            for (int off = 1; off < 16; off <<= 1) m0 = fmaxf(m0, __shfl_xor(m0, off));
            mx[r] = m0;
        }

        float alpha[4], mn[4], psum[4];
        #pragma unroll
        for (int r = 0; r < 4; ++r) {
            mn[r] = fmaxf(m_r[r], mx[r]);
            alpha[r] = __expf(m_r[r] - mn[r]);
            m_r[r] = mn[r];
            psum[r] = 0.f;
        }
        unsigned short* Pw = &Ps[wave * 16 * PSTR];
        #pragma unroll
        for (int i = 0; i < 8; ++i) {
            #pragma unroll
            for (int r = 0; r < 4; ++r) {
                float p = __expf(accS[i][r] + madv[i] - mn[r]);
                psum[r] += p;
                Pw[(qd * 4 + r) * PSTR + 16 * i + lm] = f2bu(p);
            }
        }
        #pragma unroll
        for (int r = 0; r < 4; ++r) {
            float s = psum[r];
            #pragma unroll
            for (int off = 1; off < 16; off <<= 1) s += __shfl_xor(s, off);
            l_r[r] = l_r[r] * alpha[r] + s;
            #pragma unroll
            for (int in = 0; in < 4; ++in) accO[in][r] *= alpha[r];
        }

        #pragma unroll
        for (int c = 0; c < 4; ++c) {
            frag8 pf = *reinterpret_cast<const frag8*>(&Pw[lm * PSTR + 32 * c + 8 * qd]);
            #pragma unroll
            for (int in = 0; in < 4; ++in) {
                frag8 vf = *reinterpret_cast<const frag8*>(&VTs[(16 * in + lm) * PSTR + 32 * c + 8 * qd]);
                accO[in] = __builtin_amdgcn_mfma_f32_16x16x32_bf16(pf, vf, accO[in], 0, 0, 0);
            }
        }
    }

    float inv[4];
    #pragma unroll
    for (int r = 0; r < 4; ++r) inv[r] = 1.f / l_r[r];
    #pragma unroll
    for (int in = 0; in < 4; ++in)
        #pragma unroll
        for (int r = 0; r < 4; ++r)
            ctx[((size_t)(b * SEQ + q0 + 16 * wave + qd * 4 + r)) * D_MODEL + h * DK + 16 * in + lm]
                = __float2bfloat16(accO[in][r] * inv[r]);
}

// y = alpha*(v-mean)/(std+eps)+bias, v = base + add (add always ws bf16), ddof=1.
template<bool BASE_WS, bool OUT_WS>
__global__ __launch_bounds__(256) void ln_kernel(const void* __restrict__ base,
    const bf16* __restrict__ addv, const void* __restrict__ alpha,
    const void* __restrict__ bias, void* __restrict__ outp, const int* __restrict__ flagp)
{
    const bool inF32 = (*flagp) != 0;
    __shared__ float vals[D_MODEL];
    __shared__ float red[256];
    const int row = blockIdx.x, tid = threadIdx.x;

    float lsum = 0.f;
    for (int i = tid; i < D_MODEL; i += 256) {
        const size_t off = (size_t)row * D_MODEL + i;
        float v = (BASE_WS ? toF(((const bf16*)base)[off]) : ld1(base, off, inF32)) + toF(addv[off]);
        vals[i] = v; lsum += v;
    }
    red[tid] = lsum; __syncthreads();
    for (int s = 128; s > 0; s >>= 1) { if (tid < s) red[tid] += red[tid + s]; __syncthreads(); }
    const float mean = red[0] / (float)D_MODEL; __syncthreads();

    float lsq = 0.f;
    for (int i = tid; i < D_MODEL; i += 256) { float dd = vals[i] - mean; lsq += dd * dd; }
    red[tid] = lsq; __syncthreads();
    for (int s = 128; s > 0; s >>= 1) { if (tid < s) red[tid] += red[tid + s]; __syncthreads(); }
    const float var = red[0] / (float)(D_MODEL - 1);
    const float inv = 1.f / (sqrtf(var) + LN_EPS);

    for (int i = tid; i < D_MODEL; i += 256) {
        const size_t off = (size_t)row * D_MODEL + i;
        const float y = ld1(alpha, i, inF32) * (vals[i] - mean) * inv + ld1(bias, i, inF32);
        if (OUT_WS || !inF32) ((bf16*)outp)[off] = __float2bfloat16(y);
        else                  ((float*)outp)[off] = y;
    }
}

extern "C" void kernel_launch(void* const* d_in, const int* in_sizes, int n_in,
                              void* d_out, int out_size, void* d_ws, size_t ws_size,
                              hipStream_t stream)
{
    const void* x    = d_in[0];
    const int*  mask = (const int*)d_in[1];
    const void* wq   = d_in[2];
    const void* wk   = d_in[3];
    const void* wv   = d_in[4];
    const void* wo   = d_in[5];
    const void* wo_b = d_in[6];
    const void* w1   = d_in[7];
    const void* b1   = d_in[8];
    const void* w2   = d_in[9];
    const void* b2   = d_in[10];
    const void* al1  = d_in[11];
    const void* bi1  = d_in[12];
    const void* al2  = d_in[13];
    const void* bi2  = d_in[14];

    // ws plan (56 MB + flag), strictly sequential lifetimes:
    //  [0,8)Qb [8,16)Kb [16,24)Vb
    //  [24,32) Xb (x as bf16; dead after QKV gemm) -> VTb (vtrans out)
    //  [32,38) WQKVT -> [32,40) CTXb (fattn out) -> W2T (after oproj)
    //  [0,2)  WOT over dead Qb (after fattn)
    //  [48,56) ATTb -> W1T (after ln1) -> X2b (after FF1... W1T dead after FF1)
    //  [40,48) X1b ; [0,32) FFb over dead Q/K/V/VT+WOT
    const size_t MB = 1024 * 1024;
    if (ws_size < 56 * MB + 4096) return;   // loud fail: out stays 0

    char* ws = (char*)d_ws;
    bf16* Qb    = (bf16*)(ws + 0 * MB);
    bf16* Kb    = (bf16*)(ws + 8 * MB);
    bf16* Vb    = (bf16*)(ws + 16 * MB);
    bf16* Xb    = (bf16*)(ws + 24 * MB);
    bf16* VTb   = (bf16*)(ws + 24 * MB);
    bf16* WQKVT = (bf16*)(ws + 32 * MB);
    bf16* CTXb  = (bf16*)(ws + 32 * MB);
    bf16* W2T   = (bf16*)(ws + 32 * MB);
    bf16* WOT   = (bf16*)(ws + 0 * MB);
    bf16* ATTb  = (bf16*)(ws + 48 * MB);
    bf16* W1T   = (bf16*)(ws + 48 * MB);
    bf16* X2b   = (bf16*)(ws + 48 * MB);
    bf16* X1b   = (bf16*)(ws + 40 * MB);
    bf16* FFb   = (bf16*)(ws + 0 * MB);
    int*  flagp = (int*)(ws + 56 * MB);

    probe_kernel<<<1, 256, 0, stream>>>(x, flagp);

    xcvt_kernel<<<dim3(ROWS * D_MODEL / 2048), 256, 0, stream>>>(x, Xb, flagp);

    dim3 tb(32, 8);
    transpose_kernel<<<dim3(32, 32), tb, 0, stream>>>(wq, WQKVT,           D_MODEL, D_MODEL, flagp);
    transpose_kernel<<<dim3(32, 32), tb, 0, stream>>>(wk, WQKVT + 1048576, D_MODEL, D_MODEL, flagp);
    transpose_kernel<<<dim3(32, 32), tb, 0, stream>>>(wv, WQKVT + 2097152, D_MODEL, D_MODEL, flagp);

    mgemm_kernel<false, false, 3><<<dim3(24, 32), 256, 0, stream>>>(
        Xb, WQKVT, nullptr, Qb, ROWS, D_MODEL, D_MODEL, flagp);

    vtrans_kernel<<<dim3(SEQ / 32, 2, BATCH * N_HEADS), tb, 0, stream>>>(Vb, VTb);

    fattn_kernel<<<dim3(SEQ / 64, N_HEADS, BATCH), 256, 0, stream>>>(Qb, Kb, VTb, mask, CTXb);

    transpose_kernel<<<dim3(32, 32), tb, 0, stream>>>(wo, WOT, D_MODEL, D_MODEL, flagp);
    mgemm_kernel<false, true, 1><<<dim3(8, 32), 256, 0, stream>>>(
        CTXb, WOT, wo_b, ATTb, ROWS, D_MODEL, D_MODEL, flagp);

    ln_kernel<false, true><<<ROWS, 256, 0, stream>>>(x, ATTb, al1, bi1, X1b, flagp);

    transpose_kernel<<<dim3(128, 32), tb, 0, stream>>>(w1, W1T, D_MODEL, D_FF, flagp);
    mgemm_kernel<true, true, 1><<<dim3(32, 32), 256, 0, stream>>>(
        X1b, W1T, b1, FFb, ROWS, D_FF, D_MODEL, flagp);

    transpose_kernel<<<dim3(32, 128), tb, 0, stream>>>(w2, W2T, D_FF, D_MODEL, flagp);
    mgemm_kernel<false, true, 1><<<dim3(8, 32), 256, 0, stream>>>(
        FFb, W2T, b2, X2b, ROWS, D_MODEL, D_FF, flagp);

    ln_kernel<true, false><<<ROWS, 256, 0, stream>>>(X1b, X2b, al2, bi2, d_out, flagp);
}

// Round 8
// 419.149 us; speedup vs baseline: 14.2689x; 1.0986x over previous
//
#include <hip/hip_runtime.h>
#include <hip/hip_bf16.h>

#define D_MODEL 1024
#define N_HEADS 16
#define DK      64
#define SEQ     2048
#define BATCH   2
#define D_FF    4096
#define ROWS    (BATCH*SEQ)   // 4096
#define LN_EPS  1e-6f
#define SSTR    72            // fattn Qs row stride (bf16): 64 data + 8 pad
#define KTILE   128           // fattn K-tile
#define PSTR    136           // fattn Ps stride (+8 pad)

typedef __hip_bfloat16 bf16;
typedef __attribute__((ext_vector_type(8))) short frag8;   // 8 bf16 (MFMA A/B)
typedef __attribute__((ext_vector_type(4))) float facc4;   // 4 f32 (MFMA C/D)

__device__ inline float bf2f(unsigned short u){ return __uint_as_float(((unsigned)u) << 16); }
__device__ inline float toF(bf16 v){ return __bfloat162float(v); }
__device__ inline unsigned short f2bu(float f){ bf16 h = __float2bfloat16(f); return *reinterpret_cast<unsigned short*>(&h); }

__device__ inline float ld1(const void* p, size_t idx, bool f32) {
    return f32 ? ((const float*)p)[idx] : toF(((const bf16*)p)[idx]);
}

struct U8 { unsigned short v[8]; };
__device__ inline U8 ld8bf(const void* p, size_t idx, bool f32) {
    U8 r;
    if (!f32) {
        *reinterpret_cast<uint4*>(r.v) = *reinterpret_cast<const uint4*>((const unsigned short*)p + idx);
    } else {
        const float* f = (const float*)p + idx;
        const float4 a = *reinterpret_cast<const float4*>(f);
        const float4 b = *reinterpret_cast<const float4*>(f + 4);
        r.v[0]=f2bu(a.x); r.v[1]=f2bu(a.y); r.v[2]=f2bu(a.z); r.v[3]=f2bu(a.w);
        r.v[4]=f2bu(b.x); r.v[5]=f2bu(b.y); r.v[6]=f2bu(b.z); r.v[7]=f2bu(b.w);
    }
    return r;
}

// Async global->LDS, 16B/lane. LDS dst is wave-uniform base; lane i -> dst+i*16B.
__device__ inline void gld16(const void* g, void* l) {
    __builtin_amdgcn_global_load_lds(
        reinterpret_cast<const __attribute__((address_space(1))) void*>(
            reinterpret_cast<uintptr_t>(g)),
        reinterpret_cast<__attribute__((address_space(3))) void*>(
            (unsigned int)reinterpret_cast<uintptr_t>(l)),
        16, 0, 0);
}

// Dtype probe: fp32 bits misread as bf16 give Inf/NaN/huge values.
__global__ void probe_kernel(const void* __restrict__ xp, int* __restrict__ flag) {
    __shared__ int hit;
    if (threadIdx.x == 0) hit = 0;
    __syncthreads();
    const bf16* p = (const bf16*)xp;
    int bad = 0;
    for (int i = threadIdx.x; i < 8192; i += 256) {
        float v = fabsf(toF(p[i]));
        if (!(v <= 1e5f)) bad = 1;
    }
    if (bad) atomicOr(&hit, 1);
    __syncthreads();
    if (threadIdx.x == 0) *flag = hit;   // 1 => inputs are fp32
}

// x (flag dtype) -> canonical bf16 ws buffer. 8 elems/thread.
__global__ __launch_bounds__(256) void xcvt_kernel(const void* __restrict__ x,
    bf16* __restrict__ out, const int* __restrict__ flagp)
{
    const bool f32 = (*flagp) != 0;
    const size_t i = ((size_t)blockIdx.x * 256 + threadIdx.x) * 8;
    U8 d = ld8bf(x, i, f32);
    *reinterpret_cast<uint4*>(out + i) = *reinterpret_cast<const uint4*>(d.v);
}

// WT[n][k] = W[k][n], output bf16. grid (N/32, K/32), block (32,8).
__global__ __launch_bounds__(256) void transpose_kernel(const void* __restrict__ W,
    bf16* __restrict__ WT, int K, int N, const int* __restrict__ flagp)
{
    const bool f32 = (*flagp) != 0;
    __shared__ float tile[32][33];
    const int tx = threadIdx.x, ty = threadIdx.y;
    const int n0 = blockIdx.x * 32, k0 = blockIdx.y * 32;
    #pragma unroll
    for (int r = 0; r < 4; ++r)
        tile[ty + 8*r][tx] = ld1(W, (size_t)(k0 + ty + 8*r) * N + n0 + tx, f32);
    __syncthreads();
    #pragma unroll
    for (int r = 0; r < 4; ++r)
        WT[(size_t)(n0 + ty + 8*r) * K + k0 + tx] = __float2bfloat16(tile[tx][ty + 8*r]);
}

// VT[(b*16+h)*64 + d][s] = V[(b*SEQ+s)*D_MODEL + h*64 + d]. grid (SEQ/32, 2, 32).
__global__ __launch_bounds__(256) void vtrans_kernel(const bf16* __restrict__ V,
    bf16* __restrict__ VT)
{
    __shared__ unsigned short tile[32][33];
    const int tx = threadIdx.x, ty = threadIdx.y;
    const int s0 = blockIdx.x * 32, d0 = blockIdx.y * 32;
    const int bh = blockIdx.z, b = bh >> 4, h = bh & 15;
    #pragma unroll
    for (int r = 0; r < 4; ++r)
        tile[ty + 8*r][tx] = *reinterpret_cast<const unsigned short*>(
            V + ((size_t)(b * SEQ + s0 + ty + 8*r)) * D_MODEL + h * DK + d0 + tx);
    __syncthreads();
    #pragma unroll
    for (int r = 0; r < 4; ++r)
        *reinterpret_cast<unsigned short*>(
            VT + ((size_t)(bh * DK + d0 + ty + 8*r)) * SEQ + s0 + tx) = tile[tx][ty + 8*r];
}

// MFMA GEMM: C bf16 = A[M,K] @ BT[N,K]^T (+bias)(+relu). 128x128 tile, 4 waves,
// BK=64, global_load_lds staging, XOR-swizzled unpadded LDS.
// NMAT>1: fused QKV (N==1024). SPLITK>1: blockIdx.z = K-slice, writes slice
// output at C + z*M*N; bias only on slice 0 (no RELU allowed when split).
template<bool RELU, bool BIAS, int NMAT, int SPLITK>
__global__ __launch_bounds__(256) void mgemm_kernel(const bf16* __restrict__ A,
    const bf16* __restrict__ BT, const void* __restrict__ bias,
    bf16* __restrict__ C, int M, int N, int K, const int* __restrict__ flagp)
{
    const bool inF32 = (*flagp) != 0;

    __shared__ unsigned short sA[128 * 64];   // 16 KB
    __shared__ unsigned short sB[128 * 64];   // 16 KB

    int which = 0, colb = blockIdx.x;
    if (NMAT > 1) { which = blockIdx.x >> 3; colb = blockIdx.x & 7; }
    const int kslice = (SPLITK > 1) ? blockIdx.z : 0;
    const int Kspan  = K / SPLITK;
    const int kbase  = kslice * Kspan;
    const bf16* Bp = BT + (size_t)which * N * K;
    bf16*       Cp = C  + (size_t)which * M * N + (size_t)kslice * M * N;

    const int row0 = blockIdx.y * 128;
    const int col0 = colb * 128;

    const int t    = threadIdx.x;
    const int wave = t >> 6;
    const int lane = t & 63;
    const int lm   = lane & 15;
    const int q    = lane >> 4;
    const int wm   = (wave & 1) * 64;
    const int wn   = (wave >> 1) * 64;

    facc4 acc[4][4];
    #pragma unroll
    for (int i = 0; i < 4; ++i)
        #pragma unroll
        for (int j = 0; j < 4; ++j)
            acc[i][j] = (facc4){0.f, 0.f, 0.f, 0.f};

    for (int k0 = kbase; k0 < kbase + Kspan; k0 += 64) {
        __syncthreads();
        #pragma unroll
        for (int j = 0; j < 4; ++j) {
            const int ch = (wave * 4 + j) * 64 + lane;   // 0..1023
            const int r  = ch >> 3;
            const int cs = ch & 7;
            const int c  = cs ^ (r & 7);
            gld16(A  + (size_t)(row0 + r) * K + k0 + 8 * c, &sA[(wave * 4 + j) * 512]);
            gld16(Bp + (size_t)(col0 + r) * K + k0 + 8 * c, &sB[(wave * 4 + j) * 512]);
        }
        __syncthreads();

        #pragma unroll
        for (int kk = 0; kk < 64; kk += 32) {
            const int cr = (kk >> 3) + q;
            frag8 af[4], bfr[4];
            #pragma unroll
            for (int im = 0; im < 4; ++im) {
                const int m = wm + 16 * im + lm;
                af[im] = *reinterpret_cast<const frag8*>(&sA[m * 64 + ((cr ^ (m & 7)) << 3)]);
            }
            #pragma unroll
            for (int in = 0; in < 4; ++in) {
                const int n = wn + 16 * in + lm;
                bfr[in] = *reinterpret_cast<const frag8*>(&sB[n * 64 + ((cr ^ (n & 7)) << 3)]);
            }
            #pragma unroll
            for (int im = 0; im < 4; ++im)
                #pragma unroll
                for (int in = 0; in < 4; ++in)
                    acc[im][in] = __builtin_amdgcn_mfma_f32_16x16x32_bf16(af[im], bfr[in], acc[im][in], 0, 0, 0);
        }
    }

    #pragma unroll
    for (int in = 0; in < 4; ++in) {
        const int col = col0 + wn + 16*in + lm;
        float bv = 0.f;
        if (BIAS && kslice == 0) bv = ld1(bias, col, inF32);
        #pragma unroll
        for (int im = 0; im < 4; ++im) {
            #pragma unroll
            for (int r = 0; r < 4; ++r) {
                const int row = row0 + wm + 16*im + 4*q + r;
                float v = acc[im][in][r] + bv;
                if (RELU) v = fmaxf(v, 0.f);
                Cp[(size_t)row * N + col] = __float2bfloat16(v);
            }
        }
    }
}

// MFMA flash attention v2: 64 q-rows/block, 4 waves. K-tile 128.
// K/VT staged via global_load_lds into XOR-swizzled unpadded LDS; Q fragment
// hoisted out of the K-loop; Qs overlays the Ps region (LDS ~49.5 KB -> 3 blocks/CU).
__global__ __launch_bounds__(256) void fattn_kernel(
    const bf16* __restrict__ Qg, const bf16* __restrict__ Kg,
    const bf16* __restrict__ VTg, const int* __restrict__ mask,
    bf16* __restrict__ ctx)
{
    __shared__ unsigned short sK[128 * 64];     // 16 KB, swizzled [kk][d]
    __shared__ unsigned short sV[64 * 128];     // 16 KB, swizzled [d][kk]
    __shared__ unsigned short PsU[4 * 16 * PSTR]; // 17 KB; Qs overlays [0,4608)
    __shared__ float madd[KTILE];

    const int t    = threadIdx.x;
    const int qt   = blockIdx.x;
    const int h    = blockIdx.y;
    const int b    = blockIdx.z;
    const int q0   = qt * 64;
    const int bh   = b * N_HEADS + h;
    const int wave = t >> 6;
    const int lane = t & 63;
    const int lm   = lane & 15;
    const int qd   = lane >> 4;

    // ---- stage Q (scaled by 0.125) into PsU-overlay, then hoist fragments ----
    unsigned short* Qs = PsU;
    {
        const int sr = t >> 2, sd0 = (t & 3) * 16;
        const unsigned short* src = (const unsigned short*)
            (Qg + ((size_t)(b * SEQ + q0 + sr)) * D_MODEL + h * DK + sd0);
        unsigned short qi[16], qo[16];
        *reinterpret_cast<uint4*>(&qi[0]) = *reinterpret_cast<const uint4*>(src);
        *reinterpret_cast<uint4*>(&qi[8]) = *reinterpret_cast<const uint4*>(src + 8);
        #pragma unroll
        for (int u = 0; u < 16; ++u) qo[u] = f2bu(bf2f(qi[u]) * 0.125f);
        *reinterpret_cast<uint4*>(&Qs[sr * SSTR + sd0])     = *reinterpret_cast<const uint4*>(&qo[0]);
        *reinterpret_cast<uint4*>(&Qs[sr * SSTR + sd0 + 8]) = *reinterpret_cast<const uint4*>(&qo[8]);
    }
    __syncthreads();
    frag8 qf[2];
    #pragma unroll
    for (int s2 = 0; s2 < 2; ++s2)
        qf[s2] = *reinterpret_cast<const frag8*>(&Qs[(16 * wave + lm) * SSTR + 32 * s2 + 8 * qd]);
    // loop-start __syncthreads (drains lgkm) protects Qs before first Ps write

    facc4 accO[4];
    float m_r[4], l_r[4];
    #pragma unroll
    for (int r = 0; r < 4; ++r) { m_r[r] = -1e30f; l_r[r] = 0.f; }
    #pragma unroll
    for (int in = 0; in < 4; ++in) accO[in] = (facc4){0.f, 0.f, 0.f, 0.f};

    for (int kt = 0; kt < SEQ / KTILE; ++kt) {
        const int k0 = kt * KTILE;
        __syncthreads();

        // ---- stage K [128 kk][64 d] and VT [64 d][128 kk], swizzled ----
        #pragma unroll
        for (int j = 0; j < 4; ++j) {
            const int ch = (wave * 4 + j) * 64 + lane;
            const int rK = ch >> 3, cK = (ch & 7) ^ (rK & 7);
            gld16(Kg + ((size_t)(b * SEQ + k0 + rK)) * D_MODEL + h * DK + 8 * cK,
                  &sK[(wave * 4 + j) * 512]);
            const int rV = ch >> 4, cV = (ch & 15) ^ (rV & 15);
            gld16(VTg + ((size_t)(bh * DK + rV)) * SEQ + k0 + 8 * cV,
                  &sV[(wave * 4 + j) * 512]);
        }
        if (t < KTILE) madd[t] = (mask[b * SEQ + k0 + t] == 0) ? -1e9f : 0.f;
        __syncthreads();

        // ---- S[16q][128kk] = Q @ K^T ----
        facc4 accS[8];
        #pragma unroll
        for (int i = 0; i < 8; ++i) accS[i] = (facc4){0.f, 0.f, 0.f, 0.f};
        #pragma unroll
        for (int i = 0; i < 8; ++i) {
            #pragma unroll
            for (int s2 = 0; s2 < 2; ++s2) {
                const int cr = 4 * s2 + qd;
                frag8 kf = *reinterpret_cast<const frag8*>(
                    &sK[(16 * i + lm) * 64 + ((cr ^ (lm & 7)) << 3)]);
                accS[i] = __builtin_amdgcn_mfma_f32_16x16x32_bf16(qf[s2], kf, accS[i], 0, 0, 0);
            }
        }

        float madv[8];
        #pragma unroll
        for (int i = 0; i < 8; ++i) madv[i] = madd[16 * i + lm];

        float mx[4];
        #pragma unroll
        for (int r = 0; r < 4; ++r) {
            float m0 = -1e30f;
            #pragma unroll
            for (int i = 0; i < 8; ++i) m0 = fmaxf(m0, accS[i][r] + madv[i]);
            #pragma unroll
            for (int off = 1; off < 16; off <<= 1) m0 = fmaxf(m0, __shfl_xor(m0, off));
            mx[r] = m0;
        }

        float alpha[4], mn[4], psum[4];
        #pragma unroll
        for (int r = 0; r < 4; ++r) {
            mn[r] = fmaxf(m_r[r], mx[r]);
            alpha[r] = __expf(m_r[r] - mn[r]);
            m_r[r] = mn[r];
            psum[r] = 0.f;
        }
        unsigned short* Pw = &PsU[wave * 16 * PSTR];
        #pragma unroll
        for (int i = 0; i < 8; ++i) {
            #pragma unroll
            for (int r = 0; r < 4; ++r) {
                float p = __expf(accS[i][r] + madv[i] - mn[r]);
                psum[r] += p;
                Pw[(qd * 4 + r) * PSTR + 16 * i + lm] = f2bu(p);
            }
        }
        #pragma unroll
        for (int r = 0; r < 4; ++r) {
            float s = psum[r];
            #pragma unroll
            for (int off = 1; off < 16; off <<= 1) s += __shfl_xor(s, off);
            l_r[r] = l_r[r] * alpha[r] + s;
            #pragma unroll
            for (int in = 0; in < 4; ++in) accO[in][r] *= alpha[r];
        }

        // ---- O += P @ V ----
        #pragma unroll
        for (int c = 0; c < 4; ++c) {
            frag8 pf = *reinterpret_cast<const frag8*>(&Pw[lm * PSTR + 32 * c + 8 * qd]);
            #pragma unroll
            for (int in = 0; in < 4; ++in) {
                const int cr = 4 * c + qd;
                frag8 vf = *reinterpret_cast<const frag8*>(
                    &sV[(16 * in + lm) * 128 + ((cr ^ lm) << 3)]);
                accO[in] = __builtin_amdgcn_mfma_f32_16x16x32_bf16(pf, vf, accO[in], 0, 0, 0);
            }
        }
    }

    float inv[4];
    #pragma unroll
    for (int r = 0; r < 4; ++r) inv[r] = 1.f / l_r[r];
    #pragma unroll
    for (int in = 0; in < 4; ++in)
        #pragma unroll
        for (int r = 0; r < 4; ++r)
            ctx[((size_t)(b * SEQ + q0 + 16 * wave + qd * 4 + r)) * D_MODEL + h * DK + 16 * in + lm]
                = __float2bfloat16(accO[in][r] * inv[r]);
}

// y = alpha*(v-mean)/(std+eps)+bias, v = base + add (+add2 if non-null), ddof=1.
template<bool BASE_WS, bool OUT_WS>
__global__ __launch_bounds__(256) void ln_kernel(const void* __restrict__ base,
    const bf16* __restrict__ addv, const bf16* __restrict__ addv2,
    const void* __restrict__ alpha, const void* __restrict__ bias,
    void* __restrict__ outp, const int* __restrict__ flagp)
{
    const bool inF32 = (*flagp) != 0;
    __shared__ float vals[D_MODEL];
    __shared__ float red[256];
    const int row = blockIdx.x, tid = threadIdx.x;

    float lsum = 0.f;
    for (int i = tid; i < D_MODEL; i += 256) {
        const size_t off = (size_t)row * D_MODEL + i;
        float v = (BASE_WS ? toF(((const bf16*)base)[off]) : ld1(base, off, inF32)) + toF(addv[off]);
        if (addv2) v += toF(addv2[off]);
        vals[i] = v; lsum += v;
    }
    red[tid] = lsum; __syncthreads();
    for (int s = 128; s > 0; s >>= 1) { if (tid < s) red[tid] += red[tid + s]; __syncthreads(); }
    const float mean = red[0] / (float)D_MODEL; __syncthreads();

    float lsq = 0.f;
    for (int i = tid; i < D_MODEL; i += 256) { float dd = vals[i] - mean; lsq += dd * dd; }
    red[tid] = lsq; __syncthreads();
    for (int s = 128; s > 0; s >>= 1) { if (tid < s) red[tid] += red[tid + s]; __syncthreads(); }
    const float var = red[0] / (float)(D_MODEL - 1);
    const float inv = 1.f / (sqrtf(var) + LN_EPS);

    for (int i = tid; i < D_MODEL; i += 256) {
        const size_t off = (size_t)row * D_MODEL + i;
        const float y = ld1(alpha, i, inF32) * (vals[i] - mean) * inv + ld1(bias, i, inF32);
        if (OUT_WS || !inF32) ((bf16*)outp)[off] = __float2bfloat16(y);
        else                  ((float*)outp)[off] = y;
    }
}

extern "C" void kernel_launch(void* const* d_in, const int* in_sizes, int n_in,
                              void* d_out, int out_size, void* d_ws, size_t ws_size,
                              hipStream_t stream)
{
    const void* x    = d_in[0];
    const int*  mask = (const int*)d_in[1];
    const void* wq   = d_in[2];
    const void* wk   = d_in[3];
    const void* wv   = d_in[4];
    const void* wo   = d_in[5];
    const void* wo_b = d_in[6];
    const void* w1   = d_in[7];
    const void* b1   = d_in[8];
    const void* w2   = d_in[9];
    const void* b2   = d_in[10];
    const void* al1  = d_in[11];
    const void* bi1  = d_in[12];
    const void* al2  = d_in[13];
    const void* bi2  = d_in[14];

    const size_t MB = 1024 * 1024;
    char* ws = (char*)d_ws;
    const bool SPLIT = ws_size >= 64 * MB + 4096;   // deterministic per-harness branch
    if (!SPLIT && ws_size < 56 * MB + 4096) return; // loud fail: out stays 0

    // Common ws plan:
    //  [0,8)Qb [8,16)Kb [16,24)Vb [24,32)Xb->VTb [32,38)WQKVT -> [32,40)CTXb
    //  [0,2)WOT over dead Qb ; [40,48)X1b ; [0,32)FFb over dead Q/K/V/VT
    // SPLIT (64MB): oproj/FF2 outputs at [48,56)+[56,64); W1T [48,56); W2T [32,40).
    // Fallback (56MB): single slice at [48,56); W1T [48,56); W2T [32,40).
    bf16* Qb    = (bf16*)(ws + 0 * MB);
    bf16* Kb    = (bf16*)(ws + 8 * MB);
    bf16* Vb    = (bf16*)(ws + 16 * MB);
    bf16* Xb    = (bf16*)(ws + 24 * MB);
    bf16* VTb   = (bf16*)(ws + 24 * MB);
    bf16* WQKVT = (bf16*)(ws + 32 * MB);
    bf16* CTXb  = (bf16*)(ws + 32 * MB);
    bf16* W2T   = (bf16*)(ws + 32 * MB);
    bf16* WOT   = (bf16*)(ws + 0 * MB);
    bf16* ATT0  = (bf16*)(ws + 48 * MB);
    bf16* ATT1  = (bf16*)(ws + 56 * MB);
    bf16* W1T   = (bf16*)(ws + 48 * MB);
    bf16* X20   = (bf16*)(ws + 48 * MB);
    bf16* X21   = (bf16*)(ws + 56 * MB);
    bf16* X1b   = (bf16*)(ws + 40 * MB);
    bf16* FFb   = (bf16*)(ws + 0 * MB);
    int*  flagp = (int*)(ws + (SPLIT ? 64 : 56) * MB);

    probe_kernel<<<1, 256, 0, stream>>>(x, flagp);
    xcvt_kernel<<<dim3(ROWS * D_MODEL / 2048), 256, 0, stream>>>(x, Xb, flagp);

    dim3 tb(32, 8);
    transpose_kernel<<<dim3(32, 32), tb, 0, stream>>>(wq, WQKVT,           D_MODEL, D_MODEL, flagp);
    transpose_kernel<<<dim3(32, 32), tb, 0, stream>>>(wk, WQKVT + 1048576, D_MODEL, D_MODEL, flagp);
    transpose_kernel<<<dim3(32, 32), tb, 0, stream>>>(wv, WQKVT + 2097152, D_MODEL, D_MODEL, flagp);

    mgemm_kernel<false, false, 3, 1><<<dim3(24, 32), 256, 0, stream>>>(
        Xb, WQKVT, nullptr, Qb, ROWS, D_MODEL, D_MODEL, flagp);

    vtrans_kernel<<<dim3(SEQ / 32, 2, BATCH * N_HEADS), tb, 0, stream>>>(Vb, VTb);

    fattn_kernel<<<dim3(SEQ / 64, N_HEADS, BATCH), 256, 0, stream>>>(Qb, Kb, VTb, mask, CTXb);

    transpose_kernel<<<dim3(32, 32), tb, 0, stream>>>(wo, WOT, D_MODEL, D_MODEL, flagp);

    if (SPLIT) {
        mgemm_kernel<false, true, 1, 2><<<dim3(8, 32, 2), 256, 0, stream>>>(
            CTXb, WOT, wo_b, ATT0, ROWS, D_MODEL, D_MODEL, flagp);
        ln_kernel<false, true><<<ROWS, 256, 0, stream>>>(x, ATT0, ATT1, al1, bi1, X1b, flagp);
    } else {
        mgemm_kernel<false, true, 1, 1><<<dim3(8, 32), 256, 0, stream>>>(
            CTXb, WOT, wo_b, ATT0, ROWS, D_MODEL, D_MODEL, flagp);
        ln_kernel<false, true><<<ROWS, 256, 0, stream>>>(x, ATT0, nullptr, al1, bi1, X1b, flagp);
    }

    transpose_kernel<<<dim3(128, 32), tb, 0, stream>>>(w1, W1T, D_MODEL, D_FF, flagp);
    mgemm_kernel<true, true, 1, 1><<<dim3(32, 32), 256, 0, stream>>>(
        X1b, W1T, b1, FFb, ROWS, D_FF, D_MODEL, flagp);

    transpose_kernel<<<dim3(32, 128), tb, 0, stream>>>(w2, W2T, D_FF, D_MODEL, flagp);

    if (SPLIT) {
        mgemm_kernel<false, true, 1, 2><<<dim3(8, 32, 2), 256, 0, stream>>>(
            FFb, W2T, b2, X20, ROWS, D_MODEL, D_FF, flagp);
        ln_kernel<true, false><<<ROWS, 256, 0, stream>>>(X1b, X20, X21, al2, bi2, d_out, flagp);
    } else {
        mgemm_kernel<false, true, 1, 1><<<dim3(8, 32), 256, 0, stream>>>(
            FFb, W2T, b2, X20, ROWS, D_MODEL, D_FF, flagp);
        ln_kernel<true, false><<<ROWS, 256, 0, stream>>>(X1b, X20, nullptr, al2, bi2, d_out, flagp);
    }
}

// Round 9
// 397.006 us; speedup vs baseline: 15.0647x; 1.0558x over previous
//
#include <hip/hip_runtime.h>
#include <hip/hip_bf16.h>

#define D_MODEL 1024
#define N_HEADS 16
#define DK      64
#define SEQ     2048
#define BATCH   2
#define D_FF    4096
#define ROWS    (BATCH*SEQ)   // 4096
#define LN_EPS  1e-6f
#define SSTR    72            // fattn Qs row stride (bf16): 64 data + 8 pad
#define KTILE   128           // fattn K-tile
#define PSTR    136           // fattn Ps stride (+8 pad)

typedef __hip_bfloat16 bf16;
typedef __attribute__((ext_vector_type(8))) short frag8;   // 8 bf16 (MFMA A/B)
typedef __attribute__((ext_vector_type(4))) float facc4;   // 4 f32 (MFMA C/D)

__device__ inline float bf2f(unsigned short u){ return __uint_as_float(((unsigned)u) << 16); }
__device__ inline float toF(bf16 v){ return __bfloat162float(v); }
__device__ inline unsigned short f2bu(float f){ bf16 h = __float2bfloat16(f); return *reinterpret_cast<unsigned short*>(&h); }

__device__ inline float ld1(const void* p, size_t idx, bool f32) {
    return f32 ? ((const float*)p)[idx] : toF(((const bf16*)p)[idx]);
}

struct U8 { unsigned short v[8]; };
__device__ inline U8 ld8bf(const void* p, size_t idx, bool f32) {
    U8 r;
    if (!f32) {
        *reinterpret_cast<uint4*>(r.v) = *reinterpret_cast<const uint4*>((const unsigned short*)p + idx);
    } else {
        const float* f = (const float*)p + idx;
        const float4 a = *reinterpret_cast<const float4*>(f);
        const float4 b = *reinterpret_cast<const float4*>(f + 4);
        r.v[0]=f2bu(a.x); r.v[1]=f2bu(a.y); r.v[2]=f2bu(a.z); r.v[3]=f2bu(a.w);
        r.v[4]=f2bu(b.x); r.v[5]=f2bu(b.y); r.v[6]=f2bu(b.z); r.v[7]=f2bu(b.w);
    }
    return r;
}

// Async global->LDS, 16B/lane. LDS dst is wave-uniform base; lane i -> dst+i*16B.
__device__ inline void gld16(const void* g, void* l) {
    __builtin_amdgcn_global_load_lds(
        reinterpret_cast<const __attribute__((address_space(1))) void*>(
            reinterpret_cast<uintptr_t>(g)),
        reinterpret_cast<__attribute__((address_space(3))) void*>(
            (unsigned int)reinterpret_cast<uintptr_t>(l)),
        16, 0, 0);
}

// Dtype probe: fp32 bits misread as bf16 give Inf/NaN/huge values.
__global__ void probe_kernel(const void* __restrict__ xp, int* __restrict__ flag) {
    __shared__ int hit;
    if (threadIdx.x == 0) hit = 0;
    __syncthreads();
    const bf16* p = (const bf16*)xp;
    int bad = 0;
    for (int i = threadIdx.x; i < 8192; i += 256) {
        float v = fabsf(toF(p[i]));
        if (!(v <= 1e5f)) bad = 1;
    }
    if (bad) atomicOr(&hit, 1);
    __syncthreads();
    if (threadIdx.x == 0) *flag = hit;   // 1 => inputs are fp32
}

// x (flag dtype) -> canonical bf16 ws buffer. 8 elems/thread.
__global__ __launch_bounds__(256) void xcvt_kernel(const void* __restrict__ x,
    bf16* __restrict__ out, const int* __restrict__ flagp)
{
    const bool f32 = (*flagp) != 0;
    const size_t i = ((size_t)blockIdx.x * 256 + threadIdx.x) * 8;
    U8 d = ld8bf(x, i, f32);
    *reinterpret_cast<uint4*>(out + i) = *reinterpret_cast<const uint4*>(d.v);
}

// WT[n][k] = W[k][n], output bf16. grid (N/32, K/32), block (32,8).
__global__ __launch_bounds__(256) void transpose_kernel(const void* __restrict__ W,
    bf16* __restrict__ WT, int K, int N, const int* __restrict__ flagp)
{
    const bool f32 = (*flagp) != 0;
    __shared__ float tile[32][33];
    const int tx = threadIdx.x, ty = threadIdx.y;
    const int n0 = blockIdx.x * 32, k0 = blockIdx.y * 32;
    #pragma unroll
    for (int r = 0; r < 4; ++r)
        tile[ty + 8*r][tx] = ld1(W, (size_t)(k0 + ty + 8*r) * N + n0 + tx, f32);
    __syncthreads();
    #pragma unroll
    for (int r = 0; r < 4; ++r)
        WT[(size_t)(n0 + ty + 8*r) * K + k0 + tx] = __float2bfloat16(tile[tx][ty + 8*r]);
}

// Fused transpose of 4 square 1024x1024 weights (wq,wk,wv,wo) -> WT4 slots 0..3.
__global__ __launch_bounds__(256) void transpose4_kernel(const void* __restrict__ w0,
    const void* __restrict__ w1, const void* __restrict__ w2, const void* __restrict__ w3,
    bf16* __restrict__ WT4, const int* __restrict__ flagp)
{
    const bool f32 = (*flagp) != 0;
    const int which = blockIdx.z;
    const void* W = (which == 0) ? w0 : (which == 1) ? w1 : (which == 2) ? w2 : w3;
    bf16* WT = WT4 + (size_t)which * D_MODEL * D_MODEL;
    __shared__ float tile[32][33];
    const int tx = threadIdx.x, ty = threadIdx.y;
    const int n0 = blockIdx.x * 32, k0 = blockIdx.y * 32;
    #pragma unroll
    for (int r = 0; r < 4; ++r)
        tile[ty + 8*r][tx] = ld1(W, (size_t)(k0 + ty + 8*r) * D_MODEL + n0 + tx, f32);
    __syncthreads();
    #pragma unroll
    for (int r = 0; r < 4; ++r)
        WT[(size_t)(n0 + ty + 8*r) * D_MODEL + k0 + tx] = __float2bfloat16(tile[tx][ty + 8*r]);
}

// VT[(b*16+h)*64 + d][s] = V[(b*SEQ+s)*D_MODEL + h*64 + d]. grid (SEQ/32, 2, 32).
__global__ __launch_bounds__(256) void vtrans_kernel(const bf16* __restrict__ V,
    bf16* __restrict__ VT)
{
    __shared__ unsigned short tile[32][33];
    const int tx = threadIdx.x, ty = threadIdx.y;
    const int s0 = blockIdx.x * 32, d0 = blockIdx.y * 32;
    const int bh = blockIdx.z, b = bh >> 4, h = bh & 15;
    #pragma unroll
    for (int r = 0; r < 4; ++r)
        tile[ty + 8*r][tx] = *reinterpret_cast<const unsigned short*>(
            V + ((size_t)(b * SEQ + s0 + ty + 8*r)) * D_MODEL + h * DK + d0 + tx);
    __syncthreads();
    #pragma unroll
    for (int r = 0; r < 4; ++r)
        *reinterpret_cast<unsigned short*>(
            VT + ((size_t)(bh * DK + d0 + ty + 8*r)) * SEQ + s0 + tx) = tile[tx][ty + 8*r];
}

// MFMA GEMM: C bf16 = A[M,K] @ BT[N,K]^T (+bias)(+relu). 128x128 tile, 4 waves,
// BK=64, global_load_lds staging, XOR-swizzled unpadded LDS.
// NMAT>1: fused QKV (N==1024). SPLITK>1: blockIdx.z = K-slice -> C + z*M*N.
template<bool RELU, bool BIAS, int NMAT, int SPLITK>
__global__ __launch_bounds__(256) void mgemm_kernel(const bf16* __restrict__ A,
    const bf16* __restrict__ BT, const void* __restrict__ bias,
    bf16* __restrict__ C, int M, int N, int K, const int* __restrict__ flagp)
{
    const bool inF32 = (*flagp) != 0;

    __shared__ unsigned short sA[128 * 64];   // 16 KB
    __shared__ unsigned short sB[128 * 64];   // 16 KB

    int which = 0, colb = blockIdx.x;
    if (NMAT > 1) { which = blockIdx.x >> 3; colb = blockIdx.x & 7; }
    const int kslice = (SPLITK > 1) ? blockIdx.z : 0;
    const int Kspan  = K / SPLITK;
    const int kbase  = kslice * Kspan;
    const bf16* Bp = BT + (size_t)which * N * K;
    bf16*       Cp = C  + (size_t)which * M * N + (size_t)kslice * M * N;

    const int row0 = blockIdx.y * 128;
    const int col0 = colb * 128;

    const int t    = threadIdx.x;
    const int wave = t >> 6;
    const int lane = t & 63;
    const int lm   = lane & 15;
    const int q    = lane >> 4;
    const int wm   = (wave & 1) * 64;
    const int wn   = (wave >> 1) * 64;

    facc4 acc[4][4];
    #pragma unroll
    for (int i = 0; i < 4; ++i)
        #pragma unroll
        for (int j = 0; j < 4; ++j)
            acc[i][j] = (facc4){0.f, 0.f, 0.f, 0.f};

    for (int k0 = kbase; k0 < kbase + Kspan; k0 += 64) {
        __syncthreads();
        #pragma unroll
        for (int j = 0; j < 4; ++j) {
            const int ch = (wave * 4 + j) * 64 + lane;   // 0..1023
            const int r  = ch >> 3;
            const int cs = ch & 7;
            const int c  = cs ^ (r & 7);
            gld16(A  + (size_t)(row0 + r) * K + k0 + 8 * c, &sA[(wave * 4 + j) * 512]);
            gld16(Bp + (size_t)(col0 + r) * K + k0 + 8 * c, &sB[(wave * 4 + j) * 512]);
        }
        __syncthreads();

        #pragma unroll
        for (int kk = 0; kk < 64; kk += 32) {
            const int cr = (kk >> 3) + q;
            frag8 af[4], bfr[4];
            #pragma unroll
            for (int im = 0; im < 4; ++im) {
                const int m = wm + 16 * im + lm;
                af[im] = *reinterpret_cast<const frag8*>(&sA[m * 64 + ((cr ^ (m & 7)) << 3)]);
            }
            #pragma unroll
            for (int in = 0; in < 4; ++in) {
                const int n = wn + 16 * in + lm;
                bfr[in] = *reinterpret_cast<const frag8*>(&sB[n * 64 + ((cr ^ (n & 7)) << 3)]);
            }
            #pragma unroll
            for (int im = 0; im < 4; ++im)
                #pragma unroll
                for (int in = 0; in < 4; ++in)
                    acc[im][in] = __builtin_amdgcn_mfma_f32_16x16x32_bf16(af[im], bfr[in], acc[im][in], 0, 0, 0);
        }
    }

    #pragma unroll
    for (int in = 0; in < 4; ++in) {
        const int col = col0 + wn + 16*in + lm;
        float bv = 0.f;
        if (BIAS && kslice == 0) bv = ld1(bias, col, inF32);
        #pragma unroll
        for (int im = 0; im < 4; ++im) {
            #pragma unroll
            for (int r = 0; r < 4; ++r) {
                const int row = row0 + wm + 16*im + 4*q + r;
                float v = acc[im][in][r] + bv;
                if (RELU) v = fmaxf(v, 0.f);
                Cp[(size_t)row * N + col] = __float2bfloat16(v);
            }
        }
    }
}

// MFMA flash attention v3: 128 q-rows/block, 512 threads (8 waves x 16 rows).
// K-tile 128. K/VT via global_load_lds, XOR-swizzled; Q frag hoisted;
// Qs overlays Ps. LDS ~68 KB -> 2 blocks/CU (16 waves/CU). Grid = 512 blocks.
__global__ __launch_bounds__(512) void fattn_kernel(
    const bf16* __restrict__ Qg, const bf16* __restrict__ Kg,
    const bf16* __restrict__ VTg, const int* __restrict__ mask,
    bf16* __restrict__ ctx)
{
    __shared__ unsigned short sK[128 * 64];       // 16 KB, swizzled [kk][d]
    __shared__ unsigned short sV[64 * 128];       // 16 KB, swizzled [d][kk]
    __shared__ unsigned short PsU[8 * 16 * PSTR]; // 34 KB; Qs overlays [0,18432)B
    __shared__ float madd[KTILE];

    const int t    = threadIdx.x;
    const int qt   = blockIdx.x;
    const int h    = blockIdx.y;
    const int b    = blockIdx.z;
    const int q0   = qt * 128;
    const int bh   = b * N_HEADS + h;
    const int wave = t >> 6;
    const int lane = t & 63;
    const int lm   = lane & 15;
    const int qd   = lane >> 4;

    // ---- stage Q (scaled 0.125) into PsU overlay; hoist fragments ----
    unsigned short* Qs = PsU;
    {
        const int sr = t >> 2, sd0 = (t & 3) * 16;   // 128 rows
        const unsigned short* src = (const unsigned short*)
            (Qg + ((size_t)(b * SEQ + q0 + sr)) * D_MODEL + h * DK + sd0);
        unsigned short qi[16], qo[16];
        *reinterpret_cast<uint4*>(&qi[0]) = *reinterpret_cast<const uint4*>(src);
        *reinterpret_cast<uint4*>(&qi[8]) = *reinterpret_cast<const uint4*>(src + 8);
        #pragma unroll
        for (int u = 0; u < 16; ++u) qo[u] = f2bu(bf2f(qi[u]) * 0.125f);
        *reinterpret_cast<uint4*>(&Qs[sr * SSTR + sd0])     = *reinterpret_cast<const uint4*>(&qo[0]);
        *reinterpret_cast<uint4*>(&Qs[sr * SSTR + sd0 + 8]) = *reinterpret_cast<const uint4*>(&qo[8]);
    }
    __syncthreads();
    frag8 qf[2];
    #pragma unroll
    for (int s2 = 0; s2 < 2; ++s2)
        qf[s2] = *reinterpret_cast<const frag8*>(&Qs[(16 * wave + lm) * SSTR + 32 * s2 + 8 * qd]);

    facc4 accO[4];
    float m_r[4], l_r[4];
    #pragma unroll
    for (int r = 0; r < 4; ++r) { m_r[r] = -1e30f; l_r[r] = 0.f; }
    #pragma unroll
    for (int in = 0; in < 4; ++in) accO[in] = (facc4){0.f, 0.f, 0.f, 0.f};

    for (int kt = 0; kt < SEQ / KTILE; ++kt) {
        const int k0 = kt * KTILE;
        __syncthreads();

        // ---- stage K [128][64] and VT [64][128], swizzled; 2 chunks/thread ----
        #pragma unroll
        for (int j = 0; j < 2; ++j) {
            const int ch = (wave * 2 + j) * 64 + lane;   // 0..1023
            const int rK = ch >> 3, cK = (ch & 7) ^ (rK & 7);
            gld16(Kg + ((size_t)(b * SEQ + k0 + rK)) * D_MODEL + h * DK + 8 * cK,
                  &sK[(wave * 2 + j) * 512]);
            const int rV = ch >> 4, cV = (ch & 15) ^ (rV & 15);
            gld16(VTg + ((size_t)(bh * DK + rV)) * SEQ + k0 + 8 * cV,
                  &sV[(wave * 2 + j) * 512]);
        }
        if (t < KTILE) madd[t] = (mask[b * SEQ + k0 + t] == 0) ? -1e9f : 0.f;
        __syncthreads();

        // ---- S[16q][128kk] = Q @ K^T ----
        facc4 accS[8];
        #pragma unroll
        for (int i = 0; i < 8; ++i) accS[i] = (facc4){0.f, 0.f, 0.f, 0.f};
        #pragma unroll
        for (int i = 0; i < 8; ++i) {
            #pragma unroll
            for (int s2 = 0; s2 < 2; ++s2) {
                const int cr = 4 * s2 + qd;
                frag8 kf = *reinterpret_cast<const frag8*>(
                    &sK[(16 * i + lm) * 64 + ((cr ^ (lm & 7)) << 3)]);
                accS[i] = __builtin_amdgcn_mfma_f32_16x16x32_bf16(qf[s2], kf, accS[i], 0, 0, 0);
            }
        }

        float madv[8];
        #pragma unroll
        for (int i = 0; i < 8; ++i) madv[i] = madd[16 * i + lm];

        float mx[4];
        #pragma unroll
        for (int r = 0; r < 4; ++r) {
            float m0 = -1e30f;
            #pragma unroll
            for (int i = 0; i < 8; ++i) m0 = fmaxf(m0, accS[i][r] + madv[i]);
            #pragma unroll
            for (int off = 1; off < 16; off <<= 1) m0 = fmaxf(m0, __shfl_xor(m0, off));
            mx[r] = m0;
        }

        float alpha[4], mn[4], psum[4];
        #pragma unroll
        for (int r = 0; r < 4; ++r) {
            mn[r] = fmaxf(m_r[r], mx[r]);
            alpha[r] = __expf(m_r[r] - mn[r]);
            m_r[r] = mn[r];
            psum[r] = 0.f;
        }
        unsigned short* Pw = &PsU[wave * 16 * PSTR];
        #pragma unroll
        for (int i = 0; i < 8; ++i) {
            #pragma unroll
            for (int r = 0; r < 4; ++r) {
                float p = __expf(accS[i][r] + madv[i] - mn[r]);
                psum[r] += p;
                Pw[(qd * 4 + r) * PSTR + 16 * i + lm] = f2bu(p);
            }
        }
        #pragma unroll
        for (int r = 0; r < 4; ++r) {
            float s = psum[r];
            #pragma unroll
            for (int off = 1; off < 16; off <<= 1) s += __shfl_xor(s, off);
            l_r[r] = l_r[r] * alpha[r] + s;
            #pragma unroll
            for (int in = 0; in < 4; ++in) accO[in][r] *= alpha[r];
        }

        // ---- O += P @ V ----
        #pragma unroll
        for (int c = 0; c < 4; ++c) {
            frag8 pf = *reinterpret_cast<const frag8*>(&Pw[lm * PSTR + 32 * c + 8 * qd]);
            #pragma unroll
            for (int in = 0; in < 4; ++in) {
                const int cr = 4 * c + qd;
                frag8 vf = *reinterpret_cast<const frag8*>(
                    &sV[(16 * in + lm) * 128 + ((cr ^ lm) << 3)]);
                accO[in] = __builtin_amdgcn_mfma_f32_16x16x32_bf16(pf, vf, accO[in], 0, 0, 0);
            }
        }
    }

    float inv[4];
    #pragma unroll
    for (int r = 0; r < 4; ++r) inv[r] = 1.f / l_r[r];
    #pragma unroll
    for (int in = 0; in < 4; ++in)
        #pragma unroll
        for (int r = 0; r < 4; ++r)
            ctx[((size_t)(b * SEQ + q0 + 16 * wave + qd * 4 + r)) * D_MODEL + h * DK + 16 * in + lm]
                = __float2bfloat16(accO[in][r] * inv[r]);
}

// y = alpha*(v-mean)/(std+eps)+bias, v = base + add (+add2 if non-null), ddof=1.
template<bool BASE_WS, bool OUT_WS>
__global__ __launch_bounds__(256) void ln_kernel(const void* __restrict__ base,
    const bf16* __restrict__ addv, const bf16* __restrict__ addv2,
    const void* __restrict__ alpha, const void* __restrict__ bias,
    void* __restrict__ outp, const int* __restrict__ flagp)
{
    const bool inF32 = (*flagp) != 0;
    __shared__ float vals[D_MODEL];
    __shared__ float red[256];
    const int row = blockIdx.x, tid = threadIdx.x;

    float lsum = 0.f;
    for (int i = tid; i < D_MODEL; i += 256) {
        const size_t off = (size_t)row * D_MODEL + i;
        float v = (BASE_WS ? toF(((const bf16*)base)[off]) : ld1(base, off, inF32)) + toF(addv[off]);
        if (addv2) v += toF(addv2[off]);
        vals[i] = v; lsum += v;
    }
    red[tid] = lsum; __syncthreads();
    for (int s = 128; s > 0; s >>= 1) { if (tid < s) red[tid] += red[tid + s]; __syncthreads(); }
    const float mean = red[0] / (float)D_MODEL; __syncthreads();

    float lsq = 0.f;
    for (int i = tid; i < D_MODEL; i += 256) { float dd = vals[i] - mean; lsq += dd * dd; }
    red[tid] = lsq; __syncthreads();
    for (int s = 128; s > 0; s >>= 1) { if (tid < s) red[tid] += red[tid + s]; __syncthreads(); }
    const float var = red[0] / (float)(D_MODEL - 1);
    const float inv = 1.f / (sqrtf(var) + LN_EPS);

    for (int i = tid; i < D_MODEL; i += 256) {
        const size_t off = (size_t)row * D_MODEL + i;
        const float y = ld1(alpha, i, inF32) * (vals[i] - mean) * inv + ld1(bias, i, inF32);
        if (OUT_WS || !inF32) ((bf16*)outp)[off] = __float2bfloat16(y);
        else                  ((float*)outp)[off] = y;
    }
}

extern "C" void kernel_launch(void* const* d_in, const int* in_sizes, int n_in,
                              void* d_out, int out_size, void* d_ws, size_t ws_size,
                              hipStream_t stream)
{
    const void* x    = d_in[0];
    const int*  mask = (const int*)d_in[1];
    const void* wq   = d_in[2];
    const void* wk   = d_in[3];
    const void* wv   = d_in[4];
    const void* wo   = d_in[5];
    const void* wo_b = d_in[6];
    const void* w1   = d_in[7];
    const void* b1   = d_in[8];
    const void* w2   = d_in[9];
    const void* b2   = d_in[10];
    const void* al1  = d_in[11];
    const void* bi1  = d_in[12];
    const void* al2  = d_in[13];
    const void* bi2  = d_in[14];

    const size_t MB = 1024 * 1024;
    char* ws = (char*)d_ws;
    const bool BIG = ws_size >= 64 * MB + 4096;     // R8 confirmed this branch runs
    if (!BIG && ws_size < 56 * MB + 4096) return;   // loud fail: out stays 0

    dim3 tb(32, 8);

    if (BIG) {
        // 64 MB plan, all weight transposes up-front:
        //  [0,8)Qb [8,16)Kb [16,24)Vb [24,32)Xb->VTb
        //  [32,40) WT4 (wq,wk,wv,wo) -> dead after oproj -> X20 [32,40)
        //  [40,48) W1T -> dead after FF1 -> X21 [40,48)
        //  [48,56) W2T
        //  [56,64) CTXb -> dead after oproj -> X1b [56,64)
        //  ATT0 [0,8) / ATT1 [8,16) over dead Qb/Kb; FFb [0,32) after ln1
        bf16* Qb   = (bf16*)(ws + 0 * MB);
        bf16* Kb   = (bf16*)(ws + 8 * MB);
        bf16* Vb   = (bf16*)(ws + 16 * MB);
        bf16* Xb   = (bf16*)(ws + 24 * MB);
        bf16* VTb  = (bf16*)(ws + 24 * MB);
        bf16* WT4  = (bf16*)(ws + 32 * MB);
        bf16* WOT  = WT4 + (size_t)3 * D_MODEL * D_MODEL;
        bf16* W1T  = (bf16*)(ws + 40 * MB);
        bf16* W2T  = (bf16*)(ws + 48 * MB);
        bf16* CTXb = (bf16*)(ws + 56 * MB);
        bf16* ATT0 = (bf16*)(ws + 0 * MB);
        bf16* ATT1 = (bf16*)(ws + 8 * MB);
        bf16* X1b  = (bf16*)(ws + 56 * MB);
        bf16* FFb  = (bf16*)(ws + 0 * MB);
        bf16* X20  = (bf16*)(ws + 32 * MB);
        bf16* X21  = (bf16*)(ws + 40 * MB);
        int*  flagp = (int*)(ws + 64 * MB);

        probe_kernel<<<1, 256, 0, stream>>>(x, flagp);
        xcvt_kernel<<<dim3(ROWS * D_MODEL / 2048), 256, 0, stream>>>(x, Xb, flagp);

        transpose4_kernel<<<dim3(32, 32, 4), tb, 0, stream>>>(wq, wk, wv, wo, WT4, flagp);
        transpose_kernel<<<dim3(128, 32), tb, 0, stream>>>(w1, W1T, D_MODEL, D_FF, flagp);
        transpose_kernel<<<dim3(32, 128), tb, 0, stream>>>(w2, W2T, D_FF, D_MODEL, flagp);

        mgemm_kernel<false, false, 3, 1><<<dim3(24, 32), 256, 0, stream>>>(
            Xb, WT4, nullptr, Qb, ROWS, D_MODEL, D_MODEL, flagp);

        vtrans_kernel<<<dim3(SEQ / 32, 2, BATCH * N_HEADS), tb, 0, stream>>>(Vb, VTb);

        fattn_kernel<<<dim3(SEQ / 128, N_HEADS, BATCH), 512, 0, stream>>>(Qb, Kb, VTb, mask, CTXb);

        mgemm_kernel<false, true, 1, 2><<<dim3(8, 32, 2), 256, 0, stream>>>(
            CTXb, WOT, wo_b, ATT0, ROWS, D_MODEL, D_MODEL, flagp);
        ln_kernel<false, true><<<ROWS, 256, 0, stream>>>(x, ATT0, ATT1, al1, bi1, X1b, flagp);

        mgemm_kernel<true, true, 1, 1><<<dim3(32, 32), 256, 0, stream>>>(
            X1b, W1T, b1, FFb, ROWS, D_FF, D_MODEL, flagp);

        mgemm_kernel<false, true, 1, 2><<<dim3(8, 32, 2), 256, 0, stream>>>(
            FFb, W2T, b2, X20, ROWS, D_MODEL, D_FF, flagp);
        ln_kernel<true, false><<<ROWS, 256, 0, stream>>>(X1b, X20, X21, al2, bi2, d_out, flagp);
    } else {
        // 56 MB fallback (R8 layout, no split-K).
        bf16* Qb    = (bf16*)(ws + 0 * MB);
        bf16* Kb    = (bf16*)(ws + 8 * MB);
        bf16* Vb    = (bf16*)(ws + 16 * MB);
        bf16* Xb    = (bf16*)(ws + 24 * MB);
        bf16* VTb   = (bf16*)(ws + 24 * MB);
        bf16* WQKVT = (bf16*)(ws + 32 * MB);
        bf16* CTXb  = (bf16*)(ws + 32 * MB);
        bf16* W2T   = (bf16*)(ws + 32 * MB);
        bf16* WOT   = (bf16*)(ws + 0 * MB);
        bf16* ATT0  = (bf16*)(ws + 48 * MB);
        bf16* W1T   = (bf16*)(ws + 48 * MB);
        bf16* X20   = (bf16*)(ws + 48 * MB);
        bf16* X1b   = (bf16*)(ws + 40 * MB);
        bf16* FFb   = (bf16*)(ws + 0 * MB);
        int*  flagp = (int*)(ws + 56 * MB);

        probe_kernel<<<1, 256, 0, stream>>>(x, flagp);
        xcvt_kernel<<<dim3(ROWS * D_MODEL / 2048), 256, 0, stream>>>(x, Xb, flagp);

        transpose_kernel<<<dim3(32, 32), tb, 0, stream>>>(wq, WQKVT,           D_MODEL, D_MODEL, flagp);
        transpose_kernel<<<dim3(32, 32), tb, 0, stream>>>(wk, WQKVT + 1048576, D_MODEL, D_MODEL, flagp);
        transpose_kernel<<<dim3(32, 32), tb, 0, stream>>>(wv, WQKVT + 2097152, D_MODEL, D_MODEL, flagp);

        mgemm_kernel<false, false, 3, 1><<<dim3(24, 32), 256, 0, stream>>>(
            Xb, WQKVT, nullptr, Qb, ROWS, D_MODEL, D_MODEL, flagp);

        vtrans_kernel<<<dim3(SEQ / 32, 2, BATCH * N_HEADS), tb, 0, stream>>>(Vb, VTb);

        fattn_kernel<<<dim3(SEQ / 128, N_HEADS, BATCH), 512, 0, stream>>>(Qb, Kb, VTb, mask, CTXb);

        transpose_kernel<<<dim3(32, 32), tb, 0, stream>>>(wo, WOT, D_MODEL, D_MODEL, flagp);
        mgemm_kernel<false, true, 1, 1><<<dim3(8, 32), 256, 0, stream>>>(
            CTXb, WOT, wo_b, ATT0, ROWS, D_MODEL, D_MODEL, flagp);
        ln_kernel<false, true><<<ROWS, 256, 0, stream>>>(x, ATT0, nullptr, al1, bi1, X1b, flagp);

        transpose_kernel<<<dim3(128, 32), tb, 0, stream>>>(w1, W1T, D_MODEL, D_FF, flagp);
        mgemm_kernel<true, true, 1, 1><<<dim3(32, 32), 256, 0, stream>>>(
            X1b, W1T, b1, FFb, ROWS, D_FF, D_MODEL, flagp);

        transpose_kernel<<<dim3(32, 128), tb, 0, stream>>>(w2, W2T, D_FF, D_MODEL, flagp);
        mgemm_kernel<false, true, 1, 1><<<dim3(8, 32), 256, 0, stream>>>(
            FFb, W2T, b2, X20, ROWS, D_MODEL, D_FF, flagp);
        ln_kernel<true, false><<<ROWS, 256, 0, stream>>>(X1b, X20, nullptr, al2, bi2, d_out, flagp);
    }
}